// Round 1
// baseline (23115.152 us; speedup 1.0000x reference)
//
#include <hip/hip_runtime.h>

#define T_SEQ 512
#define BATCH 64
#define HDIM 1024
#define G4H 4096
#define TBROWS (T_SEQ * BATCH)   // 32768
#define NBLK 128                 // recurrence blocks
#define UPB 8                    // hidden units per block
#define CNT_STRIDE 16            // u32s between step counters (64B)

using short8  = __attribute__((ext_vector_type(8))) short;   // 8 bf16 (4 VGPRs)
using float4v = __attribute__((ext_vector_type(4))) float;   // MFMA C/D

__device__ __forceinline__ unsigned short f2bf(float f) {
    union { float f; unsigned int u; } v; v.f = f;
    return (unsigned short)((v.u + 0x7fffu + ((v.u >> 16) & 1u)) >> 16); // RNE
}
__device__ __forceinline__ float bf2f(unsigned short b) {
    union { unsigned int u; float f; } v; v.u = ((unsigned int)b) << 16;
    return v.f;
}

// ---------------- fp32 -> bf16 bulk convert ----------------
__global__ void k_cvt(const float* __restrict__ src, unsigned short* __restrict__ dst, int n) {
    int i = (blockIdx.x * 256 + threadIdx.x) * 4;
    if (i >= n) return;                 // n % 4 == 0 for all our uses
    float4 v = *(const float4*)(src + i);
    ushort4 o;
    o.x = f2bf(v.x); o.y = f2bf(v.y); o.z = f2bf(v.z); o.w = f2bf(v.w);
    *(ushort4*)(dst + i) = o;
}

__global__ void k_bias(const float* __restrict__ a0, const float* __restrict__ b0,
                       const float* __restrict__ a1, const float* __restrict__ b1,
                       float* __restrict__ s0, float* __restrict__ s1) {
    int t = blockIdx.x * 256 + threadIdx.x;
    if (t < G4H) s0[t] = a0[t] + b0[t];
    else if (t < 2 * G4H) s1[t - G4H] = a1[t - G4H] + b1[t - G4H];
}

// ---------------- bf16 MFMA GEMM: C[M,N] = A[M,K] * B[N,K]^T + bias ----------------
// (unchanged — not the bottleneck; 128x128 tile, global_load_lds w16, XOR swizzle)
__global__ __launch_bounds__(256) void k_gemm_bt(
    const unsigned short* __restrict__ A,
    const unsigned short* __restrict__ B,
    const float* __restrict__ bias,
    unsigned short* __restrict__ C,
    int M, int N, int K)
{
    __shared__ __align__(16) unsigned short Asm[128 * 64];
    __shared__ __align__(16) unsigned short Bsm[128 * 64];

    const int w    = threadIdx.x >> 6;
    const int lane = threadIdx.x & 63;
    const int q    = lane >> 4, r15 = lane & 15;
    const int m0   = blockIdx.y * 128;
    const int n0   = blockIdx.x * 128;
    const int wm   = w & 1, wn = w >> 1;

    float4v acc[4][4];
#pragma unroll
    for (int i = 0; i < 4; i++)
#pragma unroll
        for (int j = 0; j < 4; j++) acc[i][j] = (float4v){0.f, 0.f, 0.f, 0.f};

    for (int k0 = 0; k0 < K; k0 += 64) {
        __syncthreads();
#pragma unroll
        for (int ii = 0; ii < 4; ii++) {
            int plin = (ii * 4 + w) * 64 + lane;
            int row  = plin >> 3;
            int gch  = (plin & 7) ^ (row & 7);
            const unsigned short* ga = A + (size_t)(m0 + row) * K + (k0 + gch * 8);
            const unsigned short* gb = B + (size_t)(n0 + row) * K + (k0 + gch * 8);
            __builtin_amdgcn_global_load_lds((const __attribute__((address_space(1))) void*)ga,
                                             (__attribute__((address_space(3))) void*)(Asm + plin * 8),
                                             16, 0, 0);
            __builtin_amdgcn_global_load_lds((const __attribute__((address_space(1))) void*)gb,
                                             (__attribute__((address_space(3))) void*)(Bsm + plin * 8),
                                             16, 0, 0);
        }
        __syncthreads();
#pragma unroll
        for (int kh = 0; kh < 2; kh++) {
            short8 af[4], bfr[4];
#pragma unroll
            for (int mi = 0; mi < 4; mi++) {
                int row = wm * 64 + mi * 16 + r15;
                int ch  = (kh * 4 + q) ^ (row & 7);
                af[mi]  = *(const short8*)(Asm + (row * 8 + ch) * 8);
            }
#pragma unroll
            for (int ni = 0; ni < 4; ni++) {
                int row = wn * 64 + ni * 16 + r15;
                int ch  = (kh * 4 + q) ^ (row & 7);
                bfr[ni] = *(const short8*)(Bsm + (row * 8 + ch) * 8);
            }
#pragma unroll
            for (int mi = 0; mi < 4; mi++)
#pragma unroll
                for (int ni = 0; ni < 4; ni++)
                    acc[mi][ni] = __builtin_amdgcn_mfma_f32_16x16x32_bf16(af[mi], bfr[ni], acc[mi][ni], 0, 0, 0);
        }
    }

#pragma unroll
    for (int ni = 0; ni < 4; ni++) {
        int col  = n0 + wn * 64 + ni * 16 + r15;
        float bv = bias[col];
#pragma unroll
        for (int mi = 0; mi < 4; mi++) {
            int rowb = m0 + wm * 64 + mi * 16 + q * 4;
#pragma unroll
            for (int rr = 0; rr < 4; rr++)
                C[(size_t)(rowb + rr) * N + col] = f2bf(acc[mi][ni][rr] + bv);
        }
    }
}

// ---------------- persistent LSTM recurrence ----------------
// 128 blocks x 512 threads (8 waves = 2 waves/SIMD). Block nb owns units
// [8nb, 8nb+8) -> 32 W_hh gate-rows staged in LDS bf16 hi/lo (B-fragment order,
// two j-groups of 16). Wave w = (batch-group w&3, j-group w>>2): 16 batch rows
// x 16 gate rows x full K. Grid sync: split arrive-counter / go-flag barrier
// with release-RMW + acquire-fence (one wbl2 + one inv per step).
__global__ __launch_bounds__(512) void k_lstm(
    const float* __restrict__ Whh,            // [4096][1024] fp32
    const unsigned short* __restrict__ xproj, // [T*B][4096] bf16 (bias included)
    unsigned short* __restrict__ h_hi,        // [2][B][H] bf16
    unsigned short* __restrict__ h_lo,        // [2][B][H] bf16
    unsigned short* __restrict__ out_b,       // layer0: bf16 h for layer-1 GEMM (or null)
    float* __restrict__ out_f,                // layer1: fp32 h -> d_out (or null)
    float* __restrict__ hn, float* __restrict__ cn,
    unsigned* __restrict__ bar,               // arrive counters + go flags
    int bar_base)                             // 0 for layer0, T_SEQ for layer1
{
    extern __shared__ char smem[];
    unsigned short* Whi = (unsigned short*)smem;        // [2 jg][128 kgran][16 j][8]  64 KB
    unsigned short* Wlo = Whi + 32 * HDIM;              // 64 KB
    float* glds         = (float*)(Wlo + 32 * HDIM);    // [64][33] gates (pad)

    const int nb   = blockIdx.x;
    const int tid  = threadIdx.x;
    const int lane = tid & 63;
    const int q    = lane >> 4, r15 = lane & 15;
    const int wv   = tid >> 6;        // 0..7
    const int bg   = wv & 3;          // batch group: rows [16bg, 16bg+16)
    const int jg   = wv >> 2;         // j-group: gate rows [16jg, 16jg+16)

    // ---- stage W_hh slice: fp32 -> bf16 hi/lo, B-fragment order (512 threads) ----
    {
        int j    = tid >> 4;              // 0..31, j = gate*8 + unit
        int g    = j >> 3, ui = j & 7;
        int jgs  = j >> 4, jloc = j & 15;
        size_t grow = (size_t)(g * HDIM + nb * UPB + ui) * HDIM;
        unsigned short* whiB = Whi + jgs * 16 * HDIM;
        unsigned short* wloB = Wlo + jgs * 16 * HDIM;
        int kbase = (tid & 15) * 64;
        for (int e = 0; e < 64; e += 4) {
            int k = kbase + e;
            float4 wvv = *(const float4*)(Whh + grow + k);
            float vv[4] = {wvv.x, wvv.y, wvv.z, wvv.w};
            unsigned short hs[4], ls[4];
#pragma unroll
            for (int m = 0; m < 4; m++) {
                hs[m] = f2bf(vv[m]);
                ls[m] = f2bf(vv[m] - bf2f(hs[m]));
            }
            int addr = (k >> 3) * 128 + jloc * 8 + (k & 7);   // shorts
            *(ushort4*)(whiB + addr) = (ushort4){hs[0], hs[1], hs[2], hs[3]};
            *(ushort4*)(wloB + addr) = (ushort4){ls[0], ls[1], ls[2], ls[3]};
        }
    }

    const int b_act = tid >> 3;                 // batch row for activation (0..63)
    const int u     = tid & 7;                  // local unit (0..7)
    float c = 0.f;

    // prefetch xproj for t=0 (activation-mapped; h-independent)
    unsigned short xv0, xv1, xv2, xv3;
    {
        const unsigned short* xpb = xproj + (size_t)b_act * G4H + nb * UPB + u;
        xv0 = xpb[0]; xv1 = xpb[HDIM]; xv2 = xpb[2 * HDIM]; xv3 = xpb[3 * HDIM];
    }

    __syncthreads();

    for (int t = 0; t < T_SEQ; t++) {
        const int cur = t & 1, nxt = cur ^ 1;

        // ---- recurrent GEMM: gates[b][j] += h_t . W_hh[j] (hi/lo 3-product) ----
        float4v acc0 = (float4v){0.f, 0.f, 0.f, 0.f};
        float4v acc1 = acc0, acc2 = acc0;

        if (t > 0) {
            const unsigned short* hr = h_hi + cur * (BATCH * HDIM) + (size_t)(bg * 16 + r15) * HDIM + q * 8;
            const unsigned short* lr = h_lo + cur * (BATCH * HDIM) + (size_t)(bg * 16 + r15) * HDIM + q * 8;
            const unsigned short* wb = Whi + jg * 16 * HDIM + q * 128 + r15 * 8;
            const unsigned short* wl = Wlo + jg * 16 * HDIM + q * 128 + r15 * 8;
#pragma unroll 8
            for (int kc = 0; kc < 32; kc++) {
                short8 ah = *(const short8*)(hr + kc * 32);
                short8 al = *(const short8*)(lr + kc * 32);
                short8 bh = *(const short8*)(wb + kc * 512);
                short8 bl = *(const short8*)(wl + kc * 512);
                acc0 = __builtin_amdgcn_mfma_f32_16x16x32_bf16(ah, bh, acc0, 0, 0, 0);
                acc1 = __builtin_amdgcn_mfma_f32_16x16x32_bf16(al, bh, acc1, 0, 0, 0);
                acc2 = __builtin_amdgcn_mfma_f32_16x16x32_bf16(ah, bl, acc2, 0, 0, 0);
            }
        }

        // gates -> LDS: D row=(q*4+rr) -> batch within group, col=r15 -> j within group
        {
            int brow = bg * 16 + q * 4;
#pragma unroll
            for (int rr = 0; rr < 4; rr++)
                glds[(brow + rr) * 33 + jg * 16 + r15] = acc0[rr] + acc1[rr] + acc2[rr];
        }
        __syncthreads();

        // ---- activations: thread -> (batch b_act, unit u) ----
        {
            const float* gr = glds + b_act * 33;
            float gi = gr[u]      + bf2f(xv0);
            float gf = gr[8 + u]  + bf2f(xv1);
            float gg = gr[16 + u] + bf2f(xv2);
            float go = gr[24 + u] + bf2f(xv3);

            c = (1.f / (1.f + __expf(-gf))) * c + (1.f / (1.f + __expf(-gi))) * tanhf(gg);
            float hv = (1.f / (1.f + __expf(-go))) * tanhf(c);

            unsigned short hb = f2bf(hv);
            int hidx = b_act * HDIM + nb * UPB + u;
            h_hi[nxt * (BATCH * HDIM) + hidx] = hb;
            h_lo[nxt * (BATCH * HDIM) + hidx] = f2bf(hv - bf2f(hb));

            size_t ooff = ((size_t)t * BATCH + b_act) * HDIM + nb * UPB + u;
            if (out_b) out_b[ooff] = hb;
            if (out_f) out_f[ooff] = hv;
            if (t == T_SEQ - 1) { hn[hidx] = hv; cn[hidx] = c; }
        }

        if (t == T_SEQ - 1) break;   // no barrier after final step

        // prefetch xproj for t+1 (h-independent; completes under barrier wait)
        {
            const unsigned short* xpb = xproj + ((size_t)(t + 1) * BATCH + b_act) * G4H + nb * UPB + u;
            xv0 = xpb[0]; xv1 = xpb[HDIM]; xv2 = xpb[2 * HDIM]; xv3 = xpb[3 * HDIM];
        }

        // ---- grid barrier: split arrive-counter / go-flag ----
        __syncthreads();   // drains all waves' h stores into L2 (vmcnt(0) before s_barrier)
        if (tid == 0) {
            unsigned* cnt = bar + (size_t)(bar_base + t) * CNT_STRIDE;
            unsigned* gof = bar + (size_t)(2 * T_SEQ + bar_base + t) * CNT_STRIDE;
            // release RMW: one buffer_wbl2 (L2 writeback) then the arrive-add
            unsigned old = __hip_atomic_fetch_add(cnt, 1u, __ATOMIC_RELEASE, __HIP_MEMORY_SCOPE_AGENT);
            if (old == (unsigned)(NBLK - 1)) {
                // last arriver broadcasts on a DIFFERENT line (no RMW/poll contention)
                __hip_atomic_store(gof, 1u, __ATOMIC_RELAXED, __HIP_MEMORY_SCOPE_AGENT);
            } else {
                while (__hip_atomic_load(gof, __ATOMIC_RELAXED, __HIP_MEMORY_SCOPE_AGENT) == 0u)
                    __builtin_amdgcn_s_sleep(1);
            }
            __builtin_amdgcn_fence(__ATOMIC_ACQUIRE, "agent");   // one buffer_inv: fresh h
        }
        __syncthreads();
    }
}

extern "C" void kernel_launch(void* const* d_in, const int* in_sizes, int n_in,
                              void* d_out, int out_size, void* d_ws, size_t ws_size,
                              hipStream_t stream) {
    (void)in_sizes; (void)n_in; (void)out_size; (void)ws_size;
    const float* x    = (const float*)d_in[0];
    const float* Wih0 = (const float*)d_in[1];
    const float* Whh0 = (const float*)d_in[2];
    const float* bih0 = (const float*)d_in[3];
    const float* bhh0 = (const float*)d_in[4];
    const float* Wih1 = (const float*)d_in[5];
    const float* Whh1 = (const float*)d_in[6];
    const float* bih1 = (const float*)d_in[7];
    const float* bhh1 = (const float*)d_in[8];
    float* out = (float*)d_out;

    // ---- workspace layout ----
    unsigned short* xb0   = (unsigned short*)d_ws;                 // x bf16        [TB][1024]
    unsigned short* xb1   = xb0 + (size_t)TBROWS * HDIM;           // layer0 h bf16 [TB][1024]
    unsigned short* wb0   = xb1 + (size_t)TBROWS * HDIM;           // W_ih0 bf16
    unsigned short* wb1   = wb0 + (size_t)G4H * HDIM;              // W_ih1 bf16
    unsigned short* xproj = wb1 + (size_t)G4H * HDIM;              // x_proj bf16 [TB][4096]
    unsigned short* hhi   = xproj + (size_t)TBROWS * G4H;          // h hi [2][B][H]
    unsigned short* hlo   = hhi + 2 * BATCH * HDIM;                // h lo [2][B][H]
    float* bsum0          = (float*)(hlo + 2 * BATCH * HDIM);      // b_ih+b_hh
    float* bsum1          = bsum0 + G4H;
    unsigned* bar         = (unsigned*)(bsum1 + G4H);              // arrive[2T] + go[2T], 64B apart

    float* hn0 = out + (size_t)TBROWS * HDIM;
    float* hn1 = hn0 + BATCH * HDIM;
    float* cn0 = hn1 + BATCH * HDIM;
    float* cn1 = cn0 + BATCH * HDIM;

    const unsigned lstm_lds = 32 * HDIM * 2 * 2 + 64 * 33 * 4;  // 139520 B
    static bool attr_set = false;
    if (!attr_set) {
        hipFuncSetAttribute((const void*)k_lstm,
                            hipFuncAttributeMaxDynamicSharedMemorySize, lstm_lds);
        attr_set = true;
    }

    // zero barrier counters + go flags (ws is re-poisoned before every call)
    hipMemsetAsync(bar, 0, 4 * T_SEQ * CNT_STRIDE * sizeof(unsigned), stream);

    // conversions
    k_cvt<<<(TBROWS * HDIM / 4 + 255) / 256, 256, 0, stream>>>(x, xb0, TBROWS * HDIM);
    k_cvt<<<(G4H * HDIM / 4 + 255) / 256, 256, 0, stream>>>(Wih0, wb0, G4H * HDIM);
    k_cvt<<<(G4H * HDIM / 4 + 255) / 256, 256, 0, stream>>>(Wih1, wb1, G4H * HDIM);
    k_bias<<<(2 * G4H + 255) / 256, 256, 0, stream>>>(bih0, bhh0, bih1, bhh1, bsum0, bsum1);

    dim3 gg(G4H / 128, TBROWS / 128);   // 32 x 256 blocks

    // layer 0
    k_gemm_bt<<<gg, 256, 0, stream>>>(xb0, wb0, bsum0, xproj, TBROWS, G4H, HDIM);
    {
        const float* whh = Whh0;
        const unsigned short* xp = xproj;
        unsigned short* hh = hhi; unsigned short* hl = hlo;
        unsigned short* ob = xb1;
        float* of = nullptr;
        float* hn = hn0; float* cn = cn0;
        unsigned* bp = bar; int bb = 0;
        void* args[] = {(void*)&whh, (void*)&xp, (void*)&hh, (void*)&hl,
                        (void*)&ob, (void*)&of, (void*)&hn, (void*)&cn,
                        (void*)&bp, (void*)&bb};
        hipLaunchCooperativeKernel((void*)k_lstm, dim3(NBLK), dim3(512), args, lstm_lds, stream);
    }

    // layer 1
    k_gemm_bt<<<gg, 256, 0, stream>>>(xb1, wb1, bsum1, xproj, TBROWS, G4H, HDIM);
    {
        const float* whh = Whh1;
        const unsigned short* xp = xproj;
        unsigned short* hh = hhi; unsigned short* hl = hlo;
        unsigned short* ob = nullptr;
        float* of = out;
        float* hn = hn1; float* cn = cn1;
        unsigned* bp = bar; int bb = T_SEQ;
        void* args[] = {(void*)&whh, (void*)&xp, (void*)&hh, (void*)&hl,
                        (void*)&ob, (void*)&of, (void*)&hn, (void*)&cn,
                        (void*)&bp, (void*)&bb};
        hipLaunchCooperativeKernel((void*)k_lstm, dim3(NBLK), dim3(512), args, lstm_lds, stream);
    }
}

// Round 2
// 12930.542 us; speedup vs baseline: 1.7876x; 1.7876x over previous
//
#include <hip/hip_runtime.h>

#define T_SEQ 512
#define BATCH 64
#define HDIM 1024
#define G4H 4096
#define TBROWS (T_SEQ * BATCH)   // 32768
#define NBLK 128                 // recurrence blocks
#define UPB 8                    // hidden units per block
#define CNT_STRIDE 16            // u32s between flag lines (64B)

using short8  = __attribute__((ext_vector_type(8))) short;   // 8 bf16 (4 VGPRs)
using float4v = __attribute__((ext_vector_type(4))) float;   // MFMA C/D

__device__ __forceinline__ unsigned short f2bf(float f) {
    union { float f; unsigned int u; } v; v.f = f;
    return (unsigned short)((v.u + 0x7fffu + ((v.u >> 16) & 1u)) >> 16); // RNE
}
__device__ __forceinline__ float bf2f(unsigned short b) {
    union { unsigned int u; float f; } v; v.u = ((unsigned int)b) << 16;
    return v.f;
}

// ---------------- fp32 -> bf16 bulk convert ----------------
__global__ void k_cvt(const float* __restrict__ src, unsigned short* __restrict__ dst, int n) {
    int i = (blockIdx.x * 256 + threadIdx.x) * 4;
    if (i >= n) return;                 // n % 4 == 0 for all our uses
    float4 v = *(const float4*)(src + i);
    ushort4 o;
    o.x = f2bf(v.x); o.y = f2bf(v.y); o.z = f2bf(v.z); o.w = f2bf(v.w);
    *(ushort4*)(dst + i) = o;
}

__global__ void k_bias(const float* __restrict__ a0, const float* __restrict__ b0,
                       const float* __restrict__ a1, const float* __restrict__ b1,
                       float* __restrict__ s0, float* __restrict__ s1) {
    int t = blockIdx.x * 256 + threadIdx.x;
    if (t < G4H) s0[t] = a0[t] + b0[t];
    else if (t < 2 * G4H) s1[t - G4H] = a1[t - G4H] + b1[t - G4H];
}

// ---------------- bf16 MFMA GEMM: C[M,N] = A[M,K] * B[N,K]^T + bias ----------------
// (unchanged — not the bottleneck; 128x128 tile, global_load_lds w16, XOR swizzle)
__global__ __launch_bounds__(256) void k_gemm_bt(
    const unsigned short* __restrict__ A,
    const unsigned short* __restrict__ B,
    const float* __restrict__ bias,
    unsigned short* __restrict__ C,
    int M, int N, int K)
{
    __shared__ __align__(16) unsigned short Asm[128 * 64];
    __shared__ __align__(16) unsigned short Bsm[128 * 64];

    const int w    = threadIdx.x >> 6;
    const int lane = threadIdx.x & 63;
    const int q    = lane >> 4, r15 = lane & 15;
    const int m0   = blockIdx.y * 128;
    const int n0   = blockIdx.x * 128;
    const int wm   = w & 1, wn = w >> 1;

    float4v acc[4][4];
#pragma unroll
    for (int i = 0; i < 4; i++)
#pragma unroll
        for (int j = 0; j < 4; j++) acc[i][j] = (float4v){0.f, 0.f, 0.f, 0.f};

    for (int k0 = 0; k0 < K; k0 += 64) {
        __syncthreads();
#pragma unroll
        for (int ii = 0; ii < 4; ii++) {
            int plin = (ii * 4 + w) * 64 + lane;
            int row  = plin >> 3;
            int gch  = (plin & 7) ^ (row & 7);
            const unsigned short* ga = A + (size_t)(m0 + row) * K + (k0 + gch * 8);
            const unsigned short* gb = B + (size_t)(n0 + row) * K + (k0 + gch * 8);
            __builtin_amdgcn_global_load_lds((const __attribute__((address_space(1))) void*)ga,
                                             (__attribute__((address_space(3))) void*)(Asm + plin * 8),
                                             16, 0, 0);
            __builtin_amdgcn_global_load_lds((const __attribute__((address_space(1))) void*)gb,
                                             (__attribute__((address_space(3))) void*)(Bsm + plin * 8),
                                             16, 0, 0);
        }
        __syncthreads();
#pragma unroll
        for (int kh = 0; kh < 2; kh++) {
            short8 af[4], bfr[4];
#pragma unroll
            for (int mi = 0; mi < 4; mi++) {
                int row = wm * 64 + mi * 16 + r15;
                int ch  = (kh * 4 + q) ^ (row & 7);
                af[mi]  = *(const short8*)(Asm + (row * 8 + ch) * 8);
            }
#pragma unroll
            for (int ni = 0; ni < 4; ni++) {
                int row = wn * 64 + ni * 16 + r15;
                int ch  = (kh * 4 + q) ^ (row & 7);
                bfr[ni] = *(const short8*)(Bsm + (row * 8 + ch) * 8);
            }
#pragma unroll
            for (int mi = 0; mi < 4; mi++)
#pragma unroll
                for (int ni = 0; ni < 4; ni++)
                    acc[mi][ni] = __builtin_amdgcn_mfma_f32_16x16x32_bf16(af[mi], bfr[ni], acc[mi][ni], 0, 0, 0);
        }
    }

#pragma unroll
    for (int ni = 0; ni < 4; ni++) {
        int col  = n0 + wn * 64 + ni * 16 + r15;
        float bv = bias[col];
#pragma unroll
        for (int mi = 0; mi < 4; mi++) {
            int rowb = m0 + wm * 64 + mi * 16 + q * 4;
#pragma unroll
            for (int rr = 0; rr < 4; rr++)
                C[(size_t)(rowb + rr) * N + col] = f2bf(acc[mi][ni][rr] + bv);
        }
    }
}

// ---------------- persistent LSTM recurrence ----------------
// 128 blocks x 256 threads (R0 mapping — empirically better than 512).
// Block nb owns units [8nb, 8nb+8) -> 32 W_hh gate-rows staged in LDS bf16
// hi/lo in B-fragment order, two j-groups of 16.
// NEW protocol (R2): h stored write-through via relaxed AGENT atomic u32 stores
// (no buffer_wbl2 anywhere); RMW-free tree barrier: per-block flag lines
// (value = step#), block 0 fans in with 128 parallel pollers and raises a go
// line; one acquire fence (buffer_inv) per step refreshes cached h loads.
__global__ __launch_bounds__(256) void k_lstm(
    const float* __restrict__ Whh,            // [4096][1024] fp32
    const unsigned short* __restrict__ xproj, // [T*B][4096] bf16 (bias included)
    unsigned short* __restrict__ h_hi,        // [2][B][H] bf16
    unsigned short* __restrict__ h_lo,        // [2][B][H] bf16
    unsigned short* __restrict__ out_b,       // layer0: bf16 h for layer-1 GEMM (or null)
    float* __restrict__ out_f,                // layer1: fp32 h -> d_out (or null)
    float* __restrict__ hn, float* __restrict__ cn,
    unsigned* __restrict__ bar,               // NBLK flag lines + 1 go line, 64B apart
    int bar_base)                             // 0 for layer0, T_SEQ for layer1
{
    extern __shared__ char smem[];
    unsigned short* Whi = (unsigned short*)smem;        // [2 jg][128 kgran][16 j][8]  64 KB
    unsigned short* Wlo = Whi + 32 * HDIM;              // 64 KB
    float* glds         = (float*)(Wlo + 32 * HDIM);    // [64][33] gates (pad)

    const int nb   = blockIdx.x;
    const int tid  = threadIdx.x;
    const int w    = tid >> 6;
    const int lane = tid & 63;
    const int q    = lane >> 4, r15 = lane & 15;

    // ---- stage W_hh slice: fp32 -> bf16 hi/lo, B-fragment order ----
    {
        int j    = tid >> 3;              // 0..31, j = gate*8 + unit
        int g    = j >> 3, ui = j & 7;
        int jg   = j >> 4, jloc = j & 15;
        size_t grow = (size_t)(g * HDIM + nb * UPB + ui) * HDIM;
        unsigned short* whiB = Whi + jg * 16 * HDIM;
        unsigned short* wloB = Wlo + jg * 16 * HDIM;
        int kbase = (tid & 7) * 128;
        for (int e = 0; e < 128; e += 4) {
            int k = kbase + e;
            float4 wv = *(const float4*)(Whh + grow + k);
            float vv[4] = {wv.x, wv.y, wv.z, wv.w};
            unsigned short hs[4], ls[4];
#pragma unroll
            for (int m = 0; m < 4; m++) {
                hs[m] = f2bf(vv[m]);
                ls[m] = f2bf(vv[m] - bf2f(hs[m]));
            }
            int addr = (k >> 3) * 128 + jloc * 8 + (k & 7);   // shorts
            *(ushort4*)(whiB + addr) = (ushort4){hs[0], hs[1], hs[2], hs[3]};
            *(ushort4*)(wloB + addr) = (ushort4){ls[0], ls[1], ls[2], ls[3]};
        }
    }

    const int b_act = tid >> 2;                 // batch row for activation
    const int up    = tid & 3;                  // unit pair
    const int u0    = up * 2;                   // local units u0, u0+1
    float c0 = 0.f, c1 = 0.f;

    // prefetch xproj for t=0 (h-independent)
    ushort2 xpv[4];
    {
        const unsigned short* xpb = xproj + (size_t)b_act * G4H + nb * UPB + u0;
#pragma unroll
        for (int g = 0; g < 4; g++) xpv[g] = *(const ushort2*)(xpb + g * HDIM);
    }

    __syncthreads();

    for (int t = 0; t < T_SEQ; t++) {
        const int cur = t & 1, nxt = cur ^ 1;

        // ---- recurrent GEMM: gates[b][j] += h_t . W_hh[j] (hi/lo 3-product) ----
        float4v acc[2][3];
#pragma unroll
        for (int jg = 0; jg < 2; jg++)
#pragma unroll
            for (int p = 0; p < 3; p++) acc[jg][p] = (float4v){0.f, 0.f, 0.f, 0.f};

        if (t > 0) {
            const unsigned short* hr = h_hi + cur * (BATCH * HDIM) + (size_t)(w * 16 + r15) * HDIM + q * 8;
            const unsigned short* lr = h_lo + cur * (BATCH * HDIM) + (size_t)(w * 16 + r15) * HDIM + q * 8;
#pragma unroll 4
            for (int kc = 0; kc < 32; kc++) {
                short8 ah = *(const short8*)(hr + kc * 32);
                short8 al = *(const short8*)(lr + kc * 32);
#pragma unroll
                for (int jg = 0; jg < 2; jg++) {
                    const unsigned short* bb = Whi + jg * 16 * HDIM + (kc * 4 + q) * 128 + r15 * 8;
                    const unsigned short* bl = Wlo + jg * 16 * HDIM + (kc * 4 + q) * 128 + r15 * 8;
                    short8 bh = *(const short8*)bb;
                    short8 blv = *(const short8*)bl;
                    acc[jg][0] = __builtin_amdgcn_mfma_f32_16x16x32_bf16(ah, bh,  acc[jg][0], 0, 0, 0);
                    acc[jg][1] = __builtin_amdgcn_mfma_f32_16x16x32_bf16(al, bh,  acc[jg][1], 0, 0, 0);
                    acc[jg][2] = __builtin_amdgcn_mfma_f32_16x16x32_bf16(ah, blv, acc[jg][2], 0, 0, 0);
                }
            }
        }

        // gates -> LDS: D row=(q*4+rr) -> batch, col=r15 -> j within group
#pragma unroll
        for (int jg = 0; jg < 2; jg++) {
            int brow = w * 16 + q * 4;
#pragma unroll
            for (int rr = 0; rr < 4; rr++)
                glds[(brow + rr) * 33 + jg * 16 + r15] = acc[jg][0][rr] + acc[jg][1][rr] + acc[jg][2][rr];
        }
        __syncthreads();

        // ---- activations: thread -> (batch b_act, units u0,u0+1) ----
        {
            const float* gr = glds + b_act * 33;
            float gi0 = gr[0*8 + u0]     + bf2f(xpv[0].x);
            float gi1 = gr[0*8 + u0 + 1] + bf2f(xpv[0].y);
            float gf0 = gr[1*8 + u0]     + bf2f(xpv[1].x);
            float gf1 = gr[1*8 + u0 + 1] + bf2f(xpv[1].y);
            float gg0 = gr[2*8 + u0]     + bf2f(xpv[2].x);
            float gg1 = gr[2*8 + u0 + 1] + bf2f(xpv[2].y);
            float go0 = gr[3*8 + u0]     + bf2f(xpv[3].x);
            float go1 = gr[3*8 + u0 + 1] + bf2f(xpv[3].y);

            c0 = (1.f / (1.f + __expf(-gf0))) * c0 + (1.f / (1.f + __expf(-gi0))) * tanhf(gg0);
            c1 = (1.f / (1.f + __expf(-gf1))) * c1 + (1.f / (1.f + __expf(-gi1))) * tanhf(gg1);
            float hv0 = (1.f / (1.f + __expf(-go0))) * tanhf(c0);
            float hv1 = (1.f / (1.f + __expf(-go1))) * tanhf(c1);

            unsigned short hb0 = f2bf(hv0), hb1 = f2bf(hv1);
            unsigned short lb0 = f2bf(hv0 - bf2f(hb0)), lb1 = f2bf(hv1 - bf2f(hb1));
            int hidx = b_act * HDIM + nb * UPB + u0;

            // write-through device-coherent h stores (no wbl2 needed at release)
            unsigned hpack = (unsigned)hb0 | ((unsigned)hb1 << 16);
            unsigned lpack = (unsigned)lb0 | ((unsigned)lb1 << 16);
            __hip_atomic_store((unsigned*)(h_hi + nxt * (BATCH * HDIM) + hidx), hpack,
                               __ATOMIC_RELAXED, __HIP_MEMORY_SCOPE_AGENT);
            __hip_atomic_store((unsigned*)(h_lo + nxt * (BATCH * HDIM) + hidx), lpack,
                               __ATOMIC_RELAXED, __HIP_MEMORY_SCOPE_AGENT);

            size_t ooff = ((size_t)t * BATCH + b_act) * HDIM + nb * UPB + u0;
            if (out_b) *(ushort2*)(out_b + ooff) = (ushort2){hb0, hb1};
            if (out_f) *(float2*)(out_f + ooff) = (float2){hv0, hv1};
            if (t == T_SEQ - 1) {
                hn[hidx] = hv0; hn[hidx + 1] = hv1;
                cn[hidx] = c0;  cn[hidx + 1] = c1;
            }
        }

        if (t == T_SEQ - 1) break;   // no barrier after final step

        // prefetch xproj for t+1 (h-independent; completes under barrier wait)
        {
            const unsigned short* xpb = xproj + ((size_t)(t + 1) * BATCH + b_act) * G4H + nb * UPB + u0;
#pragma unroll
            for (int g = 0; g < 4; g++) xpv[g] = *(const ushort2*)(xpb + g * HDIM);
        }

        // ---- RMW-free tree grid barrier ----
        __syncthreads();   // emits s_waitcnt vmcnt(0) before s_barrier: h stores durable at MALL
        const unsigned tgt = (unsigned)(bar_base + t + 1);
        if (tid == 0)
            __hip_atomic_store(bar + (size_t)nb * CNT_STRIDE, tgt,
                               __ATOMIC_RELAXED, __HIP_MEMORY_SCOPE_AGENT);
        if (nb == 0) {
            // fan-in: 128 parallel pollers, one flag line each
            if (tid < NBLK) {
                while (__hip_atomic_load(bar + (size_t)tid * CNT_STRIDE,
                                         __ATOMIC_RELAXED, __HIP_MEMORY_SCOPE_AGENT) < tgt)
                    __builtin_amdgcn_s_sleep(1);
            }
            __syncthreads();
            if (tid == 0)
                __hip_atomic_store(bar + (size_t)NBLK * CNT_STRIDE, tgt,
                                   __ATOMIC_RELAXED, __HIP_MEMORY_SCOPE_AGENT);
        } else {
            if (tid == 0) {
                while (__hip_atomic_load(bar + (size_t)NBLK * CNT_STRIDE,
                                         __ATOMIC_RELAXED, __HIP_MEMORY_SCOPE_AGENT) < tgt)
                    __builtin_amdgcn_s_sleep(1);
            }
        }
        if (tid == 0)
            __builtin_amdgcn_fence(__ATOMIC_ACQUIRE, "agent");   // one buffer_inv: fresh h
        __syncthreads();
    }
}

extern "C" void kernel_launch(void* const* d_in, const int* in_sizes, int n_in,
                              void* d_out, int out_size, void* d_ws, size_t ws_size,
                              hipStream_t stream) {
    (void)in_sizes; (void)n_in; (void)out_size; (void)ws_size;
    const float* x    = (const float*)d_in[0];
    const float* Wih0 = (const float*)d_in[1];
    const float* Whh0 = (const float*)d_in[2];
    const float* bih0 = (const float*)d_in[3];
    const float* bhh0 = (const float*)d_in[4];
    const float* Wih1 = (const float*)d_in[5];
    const float* Whh1 = (const float*)d_in[6];
    const float* bih1 = (const float*)d_in[7];
    const float* bhh1 = (const float*)d_in[8];
    float* out = (float*)d_out;

    // ---- workspace layout ----
    unsigned short* xb0   = (unsigned short*)d_ws;                 // x bf16        [TB][1024]
    unsigned short* xb1   = xb0 + (size_t)TBROWS * HDIM;           // layer0 h bf16 [TB][1024]
    unsigned short* wb0   = xb1 + (size_t)TBROWS * HDIM;           // W_ih0 bf16
    unsigned short* wb1   = wb0 + (size_t)G4H * HDIM;              // W_ih1 bf16
    unsigned short* xproj = wb1 + (size_t)G4H * HDIM;              // x_proj bf16 [TB][4096]
    unsigned short* hhi   = xproj + (size_t)TBROWS * G4H;          // h hi [2][B][H]
    unsigned short* hlo   = hhi + 2 * BATCH * HDIM;                // h lo [2][B][H]
    float* bsum0          = (float*)(hlo + 2 * BATCH * HDIM);      // b_ih+b_hh
    float* bsum1          = bsum0 + G4H;
    unsigned* bar         = (unsigned*)(bsum1 + G4H);              // NBLK flags + go, 64B apart

    float* hn0 = out + (size_t)TBROWS * HDIM;
    float* hn1 = hn0 + BATCH * HDIM;
    float* cn0 = hn1 + BATCH * HDIM;
    float* cn1 = cn0 + BATCH * HDIM;

    const unsigned lstm_lds = 32 * HDIM * 2 * 2 + 64 * 33 * 4;  // 139520 B
    static bool attr_set = false;
    if (!attr_set) {
        hipFuncSetAttribute((const void*)k_lstm,
                            hipFuncAttributeMaxDynamicSharedMemorySize, lstm_lds);
        attr_set = true;
    }

    // zero flag lines (ws is re-poisoned before every call)
    hipMemsetAsync(bar, 0, (NBLK + 1) * CNT_STRIDE * sizeof(unsigned), stream);

    // conversions
    k_cvt<<<(TBROWS * HDIM / 4 + 255) / 256, 256, 0, stream>>>(x, xb0, TBROWS * HDIM);
    k_cvt<<<(G4H * HDIM / 4 + 255) / 256, 256, 0, stream>>>(Wih0, wb0, G4H * HDIM);
    k_cvt<<<(G4H * HDIM / 4 + 255) / 256, 256, 0, stream>>>(Wih1, wb1, G4H * HDIM);
    k_bias<<<(2 * G4H + 255) / 256, 256, 0, stream>>>(bih0, bhh0, bih1, bhh1, bsum0, bsum1);

    dim3 gg(G4H / 128, TBROWS / 128);   // 32 x 256 blocks

    // layer 0
    k_gemm_bt<<<gg, 256, 0, stream>>>(xb0, wb0, bsum0, xproj, TBROWS, G4H, HDIM);
    {
        const float* whh = Whh0;
        const unsigned short* xp = xproj;
        unsigned short* hh = hhi; unsigned short* hl = hlo;
        unsigned short* ob = xb1;
        float* of = nullptr;
        float* hn = hn0; float* cn = cn0;
        unsigned* bp = bar; int bb = 0;
        void* args[] = {(void*)&whh, (void*)&xp, (void*)&hh, (void*)&hl,
                        (void*)&ob, (void*)&of, (void*)&hn, (void*)&cn,
                        (void*)&bp, (void*)&bb};
        hipLaunchCooperativeKernel((void*)k_lstm, dim3(NBLK), dim3(256), args, lstm_lds, stream);
    }

    // layer 1
    k_gemm_bt<<<gg, 256, 0, stream>>>(xb1, wb1, bsum1, xproj, TBROWS, G4H, HDIM);
    {
        const float* whh = Whh1;
        const unsigned short* xp = xproj;
        unsigned short* hh = hhi; unsigned short* hl = hlo;
        unsigned short* ob = nullptr;
        float* of = out;
        float* hn = hn1; float* cn = cn1;
        unsigned* bp = bar; int bb = T_SEQ;
        void* args[] = {(void*)&whh, (void*)&xp, (void*)&hh, (void*)&hl,
                        (void*)&ob, (void*)&of, (void*)&hn, (void*)&cn,
                        (void*)&bp, (void*)&bb};
        hipLaunchCooperativeKernel((void*)k_lstm, dim3(NBLK), dim3(256), args, lstm_lds, stream);
    }
}

// Round 3
// 12339.565 us; speedup vs baseline: 1.8733x; 1.0479x over previous
//
#include <hip/hip_runtime.h>

#define T_SEQ 512
#define BATCH 64
#define HDIM 1024
#define G4H 4096
#define TBROWS (T_SEQ * BATCH)   // 32768
#define NBLK 128                 // recurrence blocks
#define UPB 8                    // hidden units per block
#define CNT_STRIDE 16            // u32s between flag lines (64B)

using short8  = __attribute__((ext_vector_type(8))) short;   // 8 bf16 (4 VGPRs)
using float4v = __attribute__((ext_vector_type(4))) float;   // MFMA C/D

__device__ __forceinline__ unsigned short f2bf(float f) {
    union { float f; unsigned int u; } v; v.f = f;
    return (unsigned short)((v.u + 0x7fffu + ((v.u >> 16) & 1u)) >> 16); // RNE
}
__device__ __forceinline__ float bf2f(unsigned short b) {
    union { unsigned int u; float f; } v; v.u = ((unsigned int)b) << 16;
    return v.f;
}

// ---------------- fp32 -> bf16 bulk convert ----------------
__global__ void k_cvt(const float* __restrict__ src, unsigned short* __restrict__ dst, int n) {
    int i = (blockIdx.x * 256 + threadIdx.x) * 4;
    if (i >= n) return;                 // n % 4 == 0 for all our uses
    float4 v = *(const float4*)(src + i);
    ushort4 o;
    o.x = f2bf(v.x); o.y = f2bf(v.y); o.z = f2bf(v.z); o.w = f2bf(v.w);
    *(ushort4*)(dst + i) = o;
}

__global__ void k_bias(const float* __restrict__ a0, const float* __restrict__ b0,
                       const float* __restrict__ a1, const float* __restrict__ b1,
                       float* __restrict__ s0, float* __restrict__ s1) {
    int t = blockIdx.x * 256 + threadIdx.x;
    if (t < G4H) s0[t] = a0[t] + b0[t];
    else if (t < 2 * G4H) s1[t - G4H] = a1[t - G4H] + b1[t - G4H];
}

// ---------------- bf16 MFMA GEMM: C[M,N] = A[M,K] * B[N,K]^T + bias ----------------
__global__ __launch_bounds__(256) void k_gemm_bt(
    const unsigned short* __restrict__ A,
    const unsigned short* __restrict__ B,
    const float* __restrict__ bias,
    unsigned short* __restrict__ C,
    int M, int N, int K)
{
    __shared__ __align__(16) unsigned short Asm[128 * 64];
    __shared__ __align__(16) unsigned short Bsm[128 * 64];

    const int w    = threadIdx.x >> 6;
    const int lane = threadIdx.x & 63;
    const int q    = lane >> 4, r15 = lane & 15;
    const int m0   = blockIdx.y * 128;
    const int n0   = blockIdx.x * 128;
    const int wm   = w & 1, wn = w >> 1;

    float4v acc[4][4];
#pragma unroll
    for (int i = 0; i < 4; i++)
#pragma unroll
        for (int j = 0; j < 4; j++) acc[i][j] = (float4v){0.f, 0.f, 0.f, 0.f};

    for (int k0 = 0; k0 < K; k0 += 64) {
        __syncthreads();
#pragma unroll
        for (int ii = 0; ii < 4; ii++) {
            int plin = (ii * 4 + w) * 64 + lane;
            int row  = plin >> 3;
            int gch  = (plin & 7) ^ (row & 7);
            const unsigned short* ga = A + (size_t)(m0 + row) * K + (k0 + gch * 8);
            const unsigned short* gb = B + (size_t)(n0 + row) * K + (k0 + gch * 8);
            __builtin_amdgcn_global_load_lds((const __attribute__((address_space(1))) void*)ga,
                                             (__attribute__((address_space(3))) void*)(Asm + plin * 8),
                                             16, 0, 0);
            __builtin_amdgcn_global_load_lds((const __attribute__((address_space(1))) void*)gb,
                                             (__attribute__((address_space(3))) void*)(Bsm + plin * 8),
                                             16, 0, 0);
        }
        __syncthreads();
#pragma unroll
        for (int kh = 0; kh < 2; kh++) {
            short8 af[4], bfr[4];
#pragma unroll
            for (int mi = 0; mi < 4; mi++) {
                int row = wm * 64 + mi * 16 + r15;
                int ch  = (kh * 4 + q) ^ (row & 7);
                af[mi]  = *(const short8*)(Asm + (row * 8 + ch) * 8);
            }
#pragma unroll
            for (int ni = 0; ni < 4; ni++) {
                int row = wn * 64 + ni * 16 + r15;
                int ch  = (kh * 4 + q) ^ (row & 7);
                bfr[ni] = *(const short8*)(Bsm + (row * 8 + ch) * 8);
            }
#pragma unroll
            for (int mi = 0; mi < 4; mi++)
#pragma unroll
                for (int ni = 0; ni < 4; ni++)
                    acc[mi][ni] = __builtin_amdgcn_mfma_f32_16x16x32_bf16(af[mi], bfr[ni], acc[mi][ni], 0, 0, 0);
        }
    }

#pragma unroll
    for (int ni = 0; ni < 4; ni++) {
        int col  = n0 + wn * 64 + ni * 16 + r15;
        float bv = bias[col];
#pragma unroll
        for (int mi = 0; mi < 4; mi++) {
            int rowb = m0 + wm * 64 + mi * 16 + q * 4;
#pragma unroll
            for (int rr = 0; rr < 4; rr++)
                C[(size_t)(rowb + rr) * N + col] = f2bf(acc[mi][ni][rr] + bv);
        }
    }
}

// 16B plain (cached) global load via asm, immediate byte offset (literal token)
#define LD16(dst, ptr, OFF) \
    asm volatile("global_load_dwordx4 %0, %1, off offset:" #OFF : "=v"(dst) : "v"(ptr))

// issue one group: 8 kc x (hi,lo) = 16 loads, offsets 0..448 bytes from group base
#define ISSUE_GRP(H, L, hp, lp) do {                   \
    LD16(H[0], hp, 0);   LD16(L[0], lp, 0);            \
    LD16(H[1], hp, 64);  LD16(L[1], lp, 64);           \
    LD16(H[2], hp, 128); LD16(L[2], lp, 128);          \
    LD16(H[3], hp, 192); LD16(L[3], lp, 192);          \
    LD16(H[4], hp, 256); LD16(L[4], lp, 256);          \
    LD16(H[5], hp, 320); LD16(L[5], lp, 320);          \
    LD16(H[6], hp, 384); LD16(L[6], lp, 384);          \
    LD16(H[7], hp, 448); LD16(L[7], lp, 448);          \
} while (0)

#define VMWAIT(N) do { \
    asm volatile("s_waitcnt vmcnt(" #N ")"); \
    __builtin_amdgcn_sched_barrier(0); \
} while (0)

// MFMA one group of 8 kc (compile-time G) against W in LDS
template<int G>
__device__ __forceinline__ void mfma_group(const short8 (&ah)[8], const short8 (&al)[8],
                                           const unsigned short* Whi, const unsigned short* Wlo,
                                           int q, int r15, float4v (&acc)[2][3])
{
#pragma unroll
    for (int i = 0; i < 8; i++) {
        const int kc = G * 8 + i;
#pragma unroll
        for (int jg = 0; jg < 2; jg++) {
            const unsigned short* bb = Whi + jg * 16 * HDIM + (kc * 4 + q) * 128 + r15 * 8;
            const unsigned short* bl = Wlo + jg * 16 * HDIM + (kc * 4 + q) * 128 + r15 * 8;
            short8 bh  = *(const short8*)bb;
            short8 blv = *(const short8*)bl;
            acc[jg][0] = __builtin_amdgcn_mfma_f32_16x16x32_bf16(ah[i], bh,  acc[jg][0], 0, 0, 0);
            acc[jg][1] = __builtin_amdgcn_mfma_f32_16x16x32_bf16(al[i], bh,  acc[jg][1], 0, 0, 0);
            acc[jg][2] = __builtin_amdgcn_mfma_f32_16x16x32_bf16(ah[i], blv, acc[jg][2], 0, 0, 0);
        }
    }
}

// ---------------- persistent LSTM recurrence ----------------
// 128 blocks x 256 threads. Block nb owns units [8nb, 8nb+8).
// R3: (1) manually software-pipelined k-loop (4 groups x 8kc, 32 asm loads in
// flight, counted vmcnt(16), sched_barrier fences); (2) flat one-round-trip
// barrier (wave0 of every block polls all 128 flag lines, 2/lane; no go line);
// (3) out/hn/cn stores + xproj prefetch deferred to after the flag store.
__global__ __launch_bounds__(256) void k_lstm(
    const float* __restrict__ Whh,            // [4096][1024] fp32
    const unsigned short* __restrict__ xproj, // [T*B][4096] bf16 (bias included)
    unsigned short* __restrict__ h_hi,        // [2][B][H] bf16
    unsigned short* __restrict__ h_lo,        // [2][B][H] bf16
    unsigned short* __restrict__ out_b,       // layer0: bf16 h for layer-1 GEMM (or null)
    float* __restrict__ out_f,                // layer1: fp32 h -> d_out (or null)
    float* __restrict__ hn, float* __restrict__ cn,
    unsigned* __restrict__ bar,               // NBLK flag lines, 64B apart
    int bar_base)                             // 0 for layer0, T_SEQ for layer1
{
    extern __shared__ char smem[];
    unsigned short* Whi = (unsigned short*)smem;        // [2 jg][128 kgran][16 j][8]  64 KB
    unsigned short* Wlo = Whi + 32 * HDIM;              // 64 KB
    float* glds         = (float*)(Wlo + 32 * HDIM);    // [64][33] gates (pad)

    const int nb   = blockIdx.x;
    const int tid  = threadIdx.x;
    const int w    = tid >> 6;
    const int lane = tid & 63;
    const int q    = lane >> 4, r15 = lane & 15;

    // ---- stage W_hh slice: fp32 -> bf16 hi/lo, B-fragment order ----
    {
        int j    = tid >> 3;              // 0..31, j = gate*8 + unit
        int g    = j >> 3, ui = j & 7;
        int jg   = j >> 4, jloc = j & 15;
        size_t grow = (size_t)(g * HDIM + nb * UPB + ui) * HDIM;
        unsigned short* whiB = Whi + jg * 16 * HDIM;
        unsigned short* wloB = Wlo + jg * 16 * HDIM;
        int kbase = (tid & 7) * 128;
        for (int e = 0; e < 128; e += 4) {
            int k = kbase + e;
            float4 wv = *(const float4*)(Whh + grow + k);
            float vv[4] = {wv.x, wv.y, wv.z, wv.w};
            unsigned short hs[4], ls[4];
#pragma unroll
            for (int m = 0; m < 4; m++) {
                hs[m] = f2bf(vv[m]);
                ls[m] = f2bf(vv[m] - bf2f(hs[m]));
            }
            int addr = (k >> 3) * 128 + jloc * 8 + (k & 7);   // shorts
            *(ushort4*)(whiB + addr) = (ushort4){hs[0], hs[1], hs[2], hs[3]};
            *(ushort4*)(wloB + addr) = (ushort4){ls[0], ls[1], ls[2], ls[3]};
        }
    }

    const int b_act = tid >> 2;                 // batch row for activation
    const int up    = tid & 3;                  // unit pair
    const int u0    = up * 2;                   // local units u0, u0+1
    float c0 = 0.f, c1 = 0.f;

    // prefetch xproj for t=0 (h-independent)
    ushort2 xpv[4];
    {
        const unsigned short* xpb = xproj + (size_t)b_act * G4H + nb * UPB + u0;
#pragma unroll
        for (int g = 0; g < 4; g++) xpv[g] = *(const ushort2*)(xpb + g * HDIM);
    }

    __syncthreads();

    for (int t = 0; t < T_SEQ; t++) {
        const int cur = t & 1, nxt = cur ^ 1;

        // ---- recurrent GEMM: gates[b][j] += h_t . W_hh[j] (hi/lo 3-product) ----
        float4v acc[2][3];
#pragma unroll
        for (int jg = 0; jg < 2; jg++)
#pragma unroll
            for (int p = 0; p < 3; p++) acc[jg][p] = (float4v){0.f, 0.f, 0.f, 0.f};

        if (t > 0) {
            const unsigned short* hr = h_hi + cur * (BATCH * HDIM) + (size_t)(w * 16 + r15) * HDIM + q * 8;
            const unsigned short* lr = h_lo + cur * (BATCH * HDIM) + (size_t)(w * 16 + r15) * HDIM + q * 8;
            short8 a0h[8], a0l[8], a1h[8], a1l[8];
            __builtin_amdgcn_sched_barrier(0);
            ISSUE_GRP(a0h, a0l, hr,        lr);          // group 0 (kc 0..7)
            ISSUE_GRP(a1h, a1l, hr + 256,  lr + 256);    // group 1 (kc 8..15)
            VMWAIT(16);
            mfma_group<0>(a0h, a0l, Whi, Wlo, q, r15, acc);
            __builtin_amdgcn_sched_barrier(0);
            ISSUE_GRP(a0h, a0l, hr + 512,  lr + 512);    // group 2 (kc 16..23)
            VMWAIT(16);
            mfma_group<1>(a1h, a1l, Whi, Wlo, q, r15, acc);
            __builtin_amdgcn_sched_barrier(0);
            ISSUE_GRP(a1h, a1l, hr + 768,  lr + 768);    // group 3 (kc 24..31)
            VMWAIT(16);
            mfma_group<2>(a0h, a0l, Whi, Wlo, q, r15, acc);
            __builtin_amdgcn_sched_barrier(0);
            VMWAIT(0);
            mfma_group<3>(a1h, a1l, Whi, Wlo, q, r15, acc);
            __builtin_amdgcn_sched_barrier(0);
        }

        // gates -> LDS: D row=(q*4+rr) -> batch, col=r15 -> j within group
#pragma unroll
        for (int jg = 0; jg < 2; jg++) {
            int brow = w * 16 + q * 4;
#pragma unroll
            for (int rr = 0; rr < 4; rr++)
                glds[(brow + rr) * 33 + jg * 16 + r15] = acc[jg][0][rr] + acc[jg][1][rr] + acc[jg][2][rr];
        }
        __syncthreads();

        // ---- activations: thread -> (batch b_act, units u0,u0+1) ----
        float hv0, hv1;
        {
            const float* gr = glds + b_act * 33;
            float gi0 = gr[0*8 + u0]     + bf2f(xpv[0].x);
            float gi1 = gr[0*8 + u0 + 1] + bf2f(xpv[0].y);
            float gf0 = gr[1*8 + u0]     + bf2f(xpv[1].x);
            float gf1 = gr[1*8 + u0 + 1] + bf2f(xpv[1].y);
            float gg0 = gr[2*8 + u0]     + bf2f(xpv[2].x);
            float gg1 = gr[2*8 + u0 + 1] + bf2f(xpv[2].y);
            float go0 = gr[3*8 + u0]     + bf2f(xpv[3].x);
            float go1 = gr[3*8 + u0 + 1] + bf2f(xpv[3].y);

            c0 = (1.f / (1.f + __expf(-gf0))) * c0 + (1.f / (1.f + __expf(-gi0))) * tanhf(gg0);
            c1 = (1.f / (1.f + __expf(-gf1))) * c1 + (1.f / (1.f + __expf(-gi1))) * tanhf(gg1);
            hv0 = (1.f / (1.f + __expf(-go0))) * tanhf(c0);
            hv1 = (1.f / (1.f + __expf(-go1))) * tanhf(c1);

            unsigned short hb0 = f2bf(hv0), hb1 = f2bf(hv1);
            unsigned short lb0 = f2bf(hv0 - bf2f(hb0)), lb1 = f2bf(hv1 - bf2f(hb1));
            int hidx = b_act * HDIM + nb * UPB + u0;

            // write-through device-coherent h stores (only pre-flag traffic)
            unsigned hpack = (unsigned)hb0 | ((unsigned)hb1 << 16);
            unsigned lpack = (unsigned)lb0 | ((unsigned)lb1 << 16);
            __hip_atomic_store((unsigned*)(h_hi + nxt * (BATCH * HDIM) + hidx), hpack,
                               __ATOMIC_RELAXED, __HIP_MEMORY_SCOPE_AGENT);
            __hip_atomic_store((unsigned*)(h_lo + nxt * (BATCH * HDIM) + hidx), lpack,
                               __ATOMIC_RELAXED, __HIP_MEMORY_SCOPE_AGENT);
        }

        const unsigned tgt = (unsigned)(bar_base + t + 1);
        if (t < T_SEQ - 1) {
            __syncthreads();   // vmcnt(0) drain: h stores durable at MALL
            if (tid == 0)
                __hip_atomic_store(bar + (size_t)nb * CNT_STRIDE, tgt,
                                   __ATOMIC_RELAXED, __HIP_MEMORY_SCOPE_AGENT);
        }

        // ---- deferred stores (off the pre-flag critical path) ----
        {
            unsigned short hb0 = f2bf(hv0), hb1 = f2bf(hv1);
            size_t ooff = ((size_t)t * BATCH + b_act) * HDIM + nb * UPB + u0;
            if (out_b) *(ushort2*)(out_b + ooff) = (ushort2){hb0, hb1};
            if (out_f) *(float2*)(out_f + ooff) = (float2){hv0, hv1};
        }
        if (t == T_SEQ - 1) {
            int hidx = b_act * HDIM + nb * UPB + u0;
            hn[hidx] = hv0; hn[hidx + 1] = hv1;
            cn[hidx] = c0;  cn[hidx + 1] = c1;
            break;
        }

        // prefetch xproj for t+1 (overlaps poll; drained at next step's sync)
        {
            const unsigned short* xpb = xproj + ((size_t)(t + 1) * BATCH + b_act) * G4H + nb * UPB + u0;
#pragma unroll
            for (int g = 0; g < 4; g++) xpv[g] = *(const ushort2*)(xpb + g * HDIM);
        }

        // ---- flat barrier: wave0 polls all 128 flags (2 lines per lane) ----
        if (tid < 64) {
            unsigned* f0 = bar + (size_t)tid * CNT_STRIDE;
            unsigned* f1 = bar + (size_t)(tid + 64) * CNT_STRIDE;
            while (__hip_atomic_load(f0, __ATOMIC_RELAXED, __HIP_MEMORY_SCOPE_AGENT) < tgt)
                __builtin_amdgcn_s_sleep(1);
            while (__hip_atomic_load(f1, __ATOMIC_RELAXED, __HIP_MEMORY_SCOPE_AGENT) < tgt)
                __builtin_amdgcn_s_sleep(1);
        }
        if (tid == 0)
            __builtin_amdgcn_fence(__ATOMIC_ACQUIRE, "agent");   // buffer_inv: fresh h
        __syncthreads();
    }
}

extern "C" void kernel_launch(void* const* d_in, const int* in_sizes, int n_in,
                              void* d_out, int out_size, void* d_ws, size_t ws_size,
                              hipStream_t stream) {
    (void)in_sizes; (void)n_in; (void)out_size; (void)ws_size;
    const float* x    = (const float*)d_in[0];
    const float* Wih0 = (const float*)d_in[1];
    const float* Whh0 = (const float*)d_in[2];
    const float* bih0 = (const float*)d_in[3];
    const float* bhh0 = (const float*)d_in[4];
    const float* Wih1 = (const float*)d_in[5];
    const float* Whh1 = (const float*)d_in[6];
    const float* bih1 = (const float*)d_in[7];
    const float* bhh1 = (const float*)d_in[8];
    float* out = (float*)d_out;

    // ---- workspace layout ----
    unsigned short* xb0   = (unsigned short*)d_ws;                 // x bf16        [TB][1024]
    unsigned short* xb1   = xb0 + (size_t)TBROWS * HDIM;           // layer0 h bf16 [TB][1024]
    unsigned short* wb0   = xb1 + (size_t)TBROWS * HDIM;           // W_ih0 bf16
    unsigned short* wb1   = wb0 + (size_t)G4H * HDIM;              // W_ih1 bf16
    unsigned short* xproj = wb1 + (size_t)G4H * HDIM;              // x_proj bf16 [TB][4096]
    unsigned short* hhi   = xproj + (size_t)TBROWS * G4H;          // h hi [2][B][H]
    unsigned short* hlo   = hhi + 2 * BATCH * HDIM;                // h lo [2][B][H]
    float* bsum0          = (float*)(hlo + 2 * BATCH * HDIM);      // b_ih+b_hh
    float* bsum1          = bsum0 + G4H;
    unsigned* bar         = (unsigned*)(bsum1 + G4H);              // NBLK flag lines, 64B apart

    float* hn0 = out + (size_t)TBROWS * HDIM;
    float* hn1 = hn0 + BATCH * HDIM;
    float* cn0 = hn1 + BATCH * HDIM;
    float* cn1 = cn0 + BATCH * HDIM;

    const unsigned lstm_lds = 32 * HDIM * 2 * 2 + 64 * 33 * 4;  // 139520 B
    static bool attr_set = false;
    if (!attr_set) {
        hipFuncSetAttribute((const void*)k_lstm,
                            hipFuncAttributeMaxDynamicSharedMemorySize, lstm_lds);
        attr_set = true;
    }

    // zero flag lines (ws is re-poisoned before every call)
    hipMemsetAsync(bar, 0, (NBLK + 1) * CNT_STRIDE * sizeof(unsigned), stream);

    // conversions
    k_cvt<<<(TBROWS * HDIM / 4 + 255) / 256, 256, 0, stream>>>(x, xb0, TBROWS * HDIM);
    k_cvt<<<(G4H * HDIM / 4 + 255) / 256, 256, 0, stream>>>(Wih0, wb0, G4H * HDIM);
    k_cvt<<<(G4H * HDIM / 4 + 255) / 256, 256, 0, stream>>>(Wih1, wb1, G4H * HDIM);
    k_bias<<<(2 * G4H + 255) / 256, 256, 0, stream>>>(bih0, bhh0, bih1, bhh1, bsum0, bsum1);

    dim3 gg(G4H / 128, TBROWS / 128);   // 32 x 256 blocks

    // layer 0
    k_gemm_bt<<<gg, 256, 0, stream>>>(xb0, wb0, bsum0, xproj, TBROWS, G4H, HDIM);
    {
        const float* whh = Whh0;
        const unsigned short* xp = xproj;
        unsigned short* hh = hhi; unsigned short* hl = hlo;
        unsigned short* ob = xb1;
        float* of = nullptr;
        float* hn = hn0; float* cn = cn0;
        unsigned* bp = bar; int bb = 0;
        void* args[] = {(void*)&whh, (void*)&xp, (void*)&hh, (void*)&hl,
                        (void*)&ob, (void*)&of, (void*)&hn, (void*)&cn,
                        (void*)&bp, (void*)&bb};
        hipLaunchCooperativeKernel((void*)k_lstm, dim3(NBLK), dim3(256), args, lstm_lds, stream);
    }

    // layer 1
    k_gemm_bt<<<gg, 256, 0, stream>>>(xb1, wb1, bsum1, xproj, TBROWS, G4H, HDIM);
    {
        const float* whh = Whh1;
        const unsigned short* xp = xproj;
        unsigned short* hh = hhi; unsigned short* hl = hlo;
        unsigned short* ob = nullptr;
        float* of = out;
        float* hn = hn1; float* cn = cn1;
        unsigned* bp = bar; int bb = T_SEQ;
        void* args[] = {(void*)&whh, (void*)&xp, (void*)&hh, (void*)&hl,
                        (void*)&ob, (void*)&of, (void*)&hn, (void*)&cn,
                        (void*)&bp, (void*)&bb};
        hipLaunchCooperativeKernel((void*)k_lstm, dim3(NBLK), dim3(256), args, lstm_lds, stream);
    }
}

// Round 4
// 8763.150 us; speedup vs baseline: 2.6378x; 1.4081x over previous
//
#include <hip/hip_runtime.h>

#define T_SEQ 512
#define BATCH 64
#define HDIM 1024
#define G4H 4096
#define TBROWS (T_SEQ * BATCH)   // 32768
#define NBLK 128                 // recurrence blocks
#define UPB 8                    // hidden units per block
#define CNT_STRIDE 16            // u32s between flag lines (64B)
#define HB (NBLK * BATCH * UPB)  // shorts per h buffer (= B*H = 65536)

using short8  = __attribute__((ext_vector_type(8))) short;   // 8 bf16 (4 VGPRs)
using float4v = __attribute__((ext_vector_type(4))) float;   // MFMA C/D

__device__ __forceinline__ unsigned short f2bf(float f) {
    union { float f; unsigned int u; } v; v.f = f;
    return (unsigned short)((v.u + 0x7fffu + ((v.u >> 16) & 1u)) >> 16); // RNE
}
__device__ __forceinline__ float bf2f(unsigned short b) {
    union { unsigned int u; float f; } v; v.u = ((unsigned int)b) << 16;
    return v.f;
}

// ---------------- fp32 -> bf16 bulk convert ----------------
__global__ void k_cvt(const float* __restrict__ src, unsigned short* __restrict__ dst, int n) {
    int i = (blockIdx.x * 256 + threadIdx.x) * 4;
    if (i >= n) return;                 // n % 4 == 0 for all our uses
    float4 v = *(const float4*)(src + i);
    ushort4 o;
    o.x = f2bf(v.x); o.y = f2bf(v.y); o.z = f2bf(v.z); o.w = f2bf(v.w);
    *(ushort4*)(dst + i) = o;
}

__global__ void k_bias(const float* __restrict__ a0, const float* __restrict__ b0,
                       const float* __restrict__ a1, const float* __restrict__ b1,
                       float* __restrict__ s0, float* __restrict__ s1) {
    int t = blockIdx.x * 256 + threadIdx.x;
    if (t < G4H) s0[t] = a0[t] + b0[t];
    else if (t < 2 * G4H) s1[t - G4H] = a1[t - G4H] + b1[t - G4H];
}

// ---------------- bf16 MFMA GEMM: C[M,N] = A[M,K] * B[N,K]^T + bias ----------------
__global__ __launch_bounds__(256) void k_gemm_bt(
    const unsigned short* __restrict__ A,
    const unsigned short* __restrict__ B,
    const float* __restrict__ bias,
    unsigned short* __restrict__ C,
    int M, int N, int K)
{
    __shared__ __align__(16) unsigned short Asm[128 * 64];
    __shared__ __align__(16) unsigned short Bsm[128 * 64];

    const int w    = threadIdx.x >> 6;
    const int lane = threadIdx.x & 63;
    const int q    = lane >> 4, r15 = lane & 15;
    const int m0   = blockIdx.y * 128;
    const int n0   = blockIdx.x * 128;
    const int wm   = w & 1, wn = w >> 1;

    float4v acc[4][4];
#pragma unroll
    for (int i = 0; i < 4; i++)
#pragma unroll
        for (int j = 0; j < 4; j++) acc[i][j] = (float4v){0.f, 0.f, 0.f, 0.f};

    for (int k0 = 0; k0 < K; k0 += 64) {
        __syncthreads();
#pragma unroll
        for (int ii = 0; ii < 4; ii++) {
            int plin = (ii * 4 + w) * 64 + lane;
            int row  = plin >> 3;
            int gch  = (plin & 7) ^ (row & 7);
            const unsigned short* ga = A + (size_t)(m0 + row) * K + (k0 + gch * 8);
            const unsigned short* gb = B + (size_t)(n0 + row) * K + (k0 + gch * 8);
            __builtin_amdgcn_global_load_lds((const __attribute__((address_space(1))) void*)ga,
                                             (__attribute__((address_space(3))) void*)(Asm + plin * 8),
                                             16, 0, 0);
            __builtin_amdgcn_global_load_lds((const __attribute__((address_space(1))) void*)gb,
                                             (__attribute__((address_space(3))) void*)(Bsm + plin * 8),
                                             16, 0, 0);
        }
        __syncthreads();
#pragma unroll
        for (int kh = 0; kh < 2; kh++) {
            short8 af[4], bfr[4];
#pragma unroll
            for (int mi = 0; mi < 4; mi++) {
                int row = wm * 64 + mi * 16 + r15;
                int ch  = (kh * 4 + q) ^ (row & 7);
                af[mi]  = *(const short8*)(Asm + (row * 8 + ch) * 8);
            }
#pragma unroll
            for (int ni = 0; ni < 4; ni++) {
                int row = wn * 64 + ni * 16 + r15;
                int ch  = (kh * 4 + q) ^ (row & 7);
                bfr[ni] = *(const short8*)(Bsm + (row * 8 + ch) * 8);
            }
#pragma unroll
            for (int mi = 0; mi < 4; mi++)
#pragma unroll
                for (int ni = 0; ni < 4; ni++)
                    acc[mi][ni] = __builtin_amdgcn_mfma_f32_16x16x32_bf16(af[mi], bfr[ni], acc[mi][ni], 0, 0, 0);
        }
    }

#pragma unroll
    for (int ni = 0; ni < 4; ni++) {
        int col  = n0 + wn * 64 + ni * 16 + r15;
        float bv = bias[col];
#pragma unroll
        for (int mi = 0; mi < 4; mi++) {
            int rowb = m0 + wm * 64 + mi * 16 + q * 4;
#pragma unroll
            for (int rr = 0; rr < 4; rr++)
                C[(size_t)(rowb + rr) * N + col] = f2bf(acc[mi][ni][rr] + bv);
        }
    }
}

// uncached (device-coherent, L1+L2 bypass) 16B load/store
#define LD16U(dst, ptr) \
    asm volatile("global_load_dwordx4 %0, %1, off sc0 sc1" : "=v"(dst) : "v"(ptr))
#define ST16U(ptr, val) \
    asm volatile("global_store_dwordx4 %0, %1, off sc0 sc1" :: "v"(ptr), "v"(val) : "memory")

#define VMWAIT(N) do { \
    asm volatile("s_waitcnt vmcnt(" #N ")" ::: "memory"); \
    __builtin_amdgcn_sched_barrier(0); \
} while (0)

// gate: wait until the 32 producer blocks of k-group g have published step tgt
__device__ __forceinline__ void gate(const unsigned* prod, int g, unsigned tgt, int lane) {
    if (lane < 32) {
        const unsigned* f = prod + (size_t)(g * 32 + lane) * CNT_STRIDE;
        while (__hip_atomic_load(f, __ATOMIC_RELAXED, __HIP_MEMORY_SCOPE_AGENT) < tgt)
            __builtin_amdgcn_s_sleep(1);
    }
    __builtin_amdgcn_sched_barrier(0);
}

// issue 8 kc x (hi,lo) uncached loads for group g (chunked h layout)
__device__ __forceinline__ void issue_grp(const unsigned short* hb, const unsigned short* lb,
                                          short8 (&H)[8], short8 (&L)[8]) {
#pragma unroll
    for (int i = 0; i < 8; i++) {
        LD16U(H[i], hb + i * 2048);
        LD16U(L[i], lb + i * 2048);
    }
}

// MFMA one group of 8 kc (runtime g) against W in LDS
__device__ __forceinline__ void mfma_grp(int g, const short8 (&ah)[8], const short8 (&al)[8],
                                         const unsigned short* Whi, const unsigned short* Wlo,
                                         int q, int r15, float4v (&acc)[2][3])
{
#pragma unroll
    for (int i = 0; i < 8; i++) {
        const int kc = g * 8 + i;
#pragma unroll
        for (int jg = 0; jg < 2; jg++) {
            const unsigned short* bb = Whi + jg * 16 * HDIM + (kc * 4 + q) * 128 + r15 * 8;
            const unsigned short* bl = Wlo + jg * 16 * HDIM + (kc * 4 + q) * 128 + r15 * 8;
            short8 bh  = *(const short8*)bb;
            short8 blv = *(const short8*)bl;
            acc[jg][0] = __builtin_amdgcn_mfma_f32_16x16x32_bf16(ah[i], bh,  acc[jg][0], 0, 0, 0);
            acc[jg][1] = __builtin_amdgcn_mfma_f32_16x16x32_bf16(al[i], bh,  acc[jg][1], 0, 0, 0);
            acc[jg][2] = __builtin_amdgcn_mfma_f32_16x16x32_bf16(ah[i], blv, acc[jg][2], 0, 0, 0);
        }
    }
}

// ---------------- persistent LSTM recurrence ----------------
// R4: no grid barrier. h in chunked layout [2][NBLK][64][8] bf16 hi/lo; all h
// traffic uncached (sc0 sc1) so no fences/invalidate anywhere. Producer block
// nb: act -> LDS transpose -> wave0 wide stores -> vmcnt(0) -> flag[nb]=t+1.
// Consumer k-loop gates each 8-kc group (32 producers) just-in-time, staggered
// start at group nb&3, pipelined 2 groups deep. WAR protection via per-step
// done[t] counter (consumers add after loads returned; producers check t-1).
__global__ __launch_bounds__(256) void k_lstm(
    const float* __restrict__ Whh,            // [4096][1024] fp32
    const unsigned short* __restrict__ xproj, // [T*B][4096] bf16 (bias included)
    unsigned short* __restrict__ h_hi,        // [2][NBLK][64][8] bf16 chunked
    unsigned short* __restrict__ h_lo,        // [2][NBLK][64][8] bf16 chunked
    unsigned short* __restrict__ out_b,       // layer0: bf16 h for layer-1 GEMM (or null)
    float* __restrict__ out_f,                // layer1: fp32 h -> d_out (or null)
    float* __restrict__ hn, float* __restrict__ cn,
    unsigned* __restrict__ bar,               // [NBLK] prod flags + [2*T_SEQ] done lines
    int bar_base)                             // 0 for layer0, T_SEQ for layer1
{
    extern __shared__ char smem[];
    unsigned short* Whi = (unsigned short*)smem;        // [2 jg][128 kgran][16 j][8]  64 KB
    unsigned short* Wlo = Whi + 32 * HDIM;              // 64 KB
    float* glds         = (float*)(Wlo + 32 * HDIM);    // [64][33] gates (pad)
    unsigned short* stg_hi = (unsigned short*)(glds + 64 * 33);  // [64][8]
    unsigned short* stg_lo = stg_hi + 64 * 8;                    // [64][8]

    const int nb   = blockIdx.x;
    const int tid  = threadIdx.x;
    const int w    = tid >> 6;
    const int lane = tid & 63;
    const int q    = lane >> 4, r15 = lane & 15;
    const int brow = w * 16 + r15;

    unsigned* prod = bar;                          // NBLK flag lines
    unsigned* done = bar + NBLK * CNT_STRIDE;      // per-abs-step counter lines

    // ---- stage W_hh slice: fp32 -> bf16 hi/lo, B-fragment order ----
    {
        int j    = tid >> 3;              // 0..31, j = gate*8 + unit
        int g    = j >> 3, ui = j & 7;
        int jg   = j >> 4, jloc = j & 15;
        size_t grow = (size_t)(g * HDIM + nb * UPB + ui) * HDIM;
        unsigned short* whiB = Whi + jg * 16 * HDIM;
        unsigned short* wloB = Wlo + jg * 16 * HDIM;
        int kbase = (tid & 7) * 128;
        for (int e = 0; e < 128; e += 4) {
            int k = kbase + e;
            float4 wv = *(const float4*)(Whh + grow + k);
            float vv[4] = {wv.x, wv.y, wv.z, wv.w};
            unsigned short hs[4], ls[4];
#pragma unroll
            for (int m = 0; m < 4; m++) {
                hs[m] = f2bf(vv[m]);
                ls[m] = f2bf(vv[m] - bf2f(hs[m]));
            }
            int addr = (k >> 3) * 128 + jloc * 8 + (k & 7);   // shorts
            *(ushort4*)(whiB + addr) = (ushort4){hs[0], hs[1], hs[2], hs[3]};
            *(ushort4*)(wloB + addr) = (ushort4){ls[0], ls[1], ls[2], ls[3]};
        }
    }

    const int b_act = tid >> 2;                 // batch row for activation
    const int u0    = (tid & 3) * 2;            // local units u0, u0+1
    float c0 = 0.f, c1 = 0.f;

    // prefetch xproj for t=0 (h-independent)
    ushort2 xpv[4];
    {
        const unsigned short* xpb = xproj + (size_t)b_act * G4H + nb * UPB + u0;
#pragma unroll
        for (int g = 0; g < 4; g++) xpv[g] = *(const ushort2*)(xpb + g * HDIM);
    }

    __syncthreads();

    for (int t = 0; t < T_SEQ; t++) {
        const int cur = t & 1, nxt = cur ^ 1;
        const unsigned tgt = (unsigned)(bar_base + t);   // flag value that publishes h_t

        // prefetch WAR check value (1-step-slack done counter), resolved at store time
        unsigned done_pre = NBLK;
        if (t >= 2 && tid < 64)
            done_pre = __hip_atomic_load(done + (size_t)(bar_base + t - 1) * CNT_STRIDE,
                                         __ATOMIC_RELAXED, __HIP_MEMORY_SCOPE_AGENT);

        // ---- recurrent GEMM: gates[b][j] += h_t . W_hh[j] (hi/lo 3-product) ----
        float4v acc[2][3];
#pragma unroll
        for (int jg = 0; jg < 2; jg++)
#pragma unroll
            for (int p = 0; p < 3; p++) acc[jg][p] = (float4v){0.f, 0.f, 0.f, 0.f};

        if (t > 0) {
            const unsigned short* hbase = h_hi + (size_t)cur * HB + q * 512 + brow * 8;
            const unsigned short* lbase = h_lo + (size_t)cur * HB + q * 512 + brow * 8;
            short8 H0[8], L0[8], H1[8], L1[8];
            const int g0 = nb & 3;
            const int gA = g0, gB = (g0 + 1) & 3, gC = (g0 + 2) & 3, gD = (g0 + 3) & 3;

            gate(prod, gA, tgt, lane);
            issue_grp(hbase + gA * 16384, lbase + gA * 16384, H0, L0);
            gate(prod, gB, tgt, lane);
            issue_grp(hbase + gB * 16384, lbase + gB * 16384, H1, L1);
            VMWAIT(16);
            mfma_grp(gA, H0, L0, Whi, Wlo, q, r15, acc);
            gate(prod, gC, tgt, lane);
            issue_grp(hbase + gC * 16384, lbase + gC * 16384, H0, L0);
            VMWAIT(16);
            mfma_grp(gB, H1, L1, Whi, Wlo, q, r15, acc);
            gate(prod, gD, tgt, lane);
            issue_grp(hbase + gD * 16384, lbase + gD * 16384, H1, L1);
            VMWAIT(16);
            mfma_grp(gC, H0, L0, Whi, Wlo, q, r15, acc);
            VMWAIT(0);
            mfma_grp(gD, H1, L1, Whi, Wlo, q, r15, acc);
        }

        // gates -> LDS: D row=(q*4+rr) -> batch, col=r15 -> j within group
#pragma unroll
        for (int jg = 0; jg < 2; jg++) {
            int browg = w * 16 + q * 4;
#pragma unroll
            for (int rr = 0; rr < 4; rr++)
                glds[(browg + rr) * 33 + jg * 16 + r15] = acc[jg][0][rr] + acc[jg][1][rr] + acc[jg][2][rr];
        }
        __syncthreads();   // gates visible; also: all waves' h loads of step t retired

        if (t > 0 && tid == 0)
            __hip_atomic_fetch_add(done + (size_t)(bar_base + t) * CNT_STRIDE, 1u,
                                   __ATOMIC_RELAXED, __HIP_MEMORY_SCOPE_AGENT);

        // ---- activations: thread -> (batch b_act, units u0,u0+1) ----
        float hv0, hv1;
        {
            const float* gr = glds + b_act * 33;
            float gi0 = gr[0*8 + u0]     + bf2f(xpv[0].x);
            float gi1 = gr[0*8 + u0 + 1] + bf2f(xpv[0].y);
            float gf0 = gr[1*8 + u0]     + bf2f(xpv[1].x);
            float gf1 = gr[1*8 + u0 + 1] + bf2f(xpv[1].y);
            float gg0 = gr[2*8 + u0]     + bf2f(xpv[2].x);
            float gg1 = gr[2*8 + u0 + 1] + bf2f(xpv[2].y);
            float go0 = gr[3*8 + u0]     + bf2f(xpv[3].x);
            float go1 = gr[3*8 + u0 + 1] + bf2f(xpv[3].y);

            c0 = (1.f / (1.f + __expf(-gf0))) * c0 + (1.f / (1.f + __expf(-gi0))) * tanhf(gg0);
            c1 = (1.f / (1.f + __expf(-gf1))) * c1 + (1.f / (1.f + __expf(-gi1))) * tanhf(gg1);
            hv0 = (1.f / (1.f + __expf(-go0))) * tanhf(c0);
            hv1 = (1.f / (1.f + __expf(-go1))) * tanhf(c1);
        }
        unsigned short hb0 = f2bf(hv0), hb1 = f2bf(hv1);

        if (t == T_SEQ - 1) {
            size_t ooff = ((size_t)t * BATCH + b_act) * HDIM + nb * UPB + u0;
            if (out_b) *(ushort2*)(out_b + ooff) = (ushort2){hb0, hb1};
            if (out_f) *(float2*)(out_f + ooff) = (float2){hv0, hv1};
            int hidx = b_act * HDIM + nb * UPB + u0;
            hn[hidx] = hv0; hn[hidx + 1] = hv1;
            cn[hidx] = c0;  cn[hidx + 1] = c1;
            break;
        }

        // ---- stage h chunk in LDS for wide stores ----
        *(ushort2*)(stg_hi + b_act * 8 + u0) = (ushort2){hb0, hb1};
        *(ushort2*)(stg_lo + b_act * 8 + u0) =
            (ushort2){f2bf(hv0 - bf2f(hb0)), f2bf(hv1 - bf2f(hb1))};
        __syncthreads();

        // ---- wave0: WAR gate, wide uncached h stores, publish flag ----
        if (tid < 64) {
            while (done_pre < (unsigned)NBLK) {
                __builtin_amdgcn_s_sleep(1);
                done_pre = __hip_atomic_load(done + (size_t)(bar_base + t - 1) * CNT_STRIDE,
                                             __ATOMIC_RELAXED, __HIP_MEMORY_SCOPE_AGENT);
            }
            __builtin_amdgcn_sched_barrier(0);
            short8 sh = *(const short8*)(stg_hi + tid * 8);
            short8 sl = *(const short8*)(stg_lo + tid * 8);
            unsigned short* dh = h_hi + (size_t)nxt * HB + nb * 512 + tid * 8;
            unsigned short* dl = h_lo + (size_t)nxt * HB + nb * 512 + tid * 8;
            ST16U(dh, sh);
            ST16U(dl, sl);
            asm volatile("s_waitcnt vmcnt(0)" ::: "memory");   // h durable at MALL
            __builtin_amdgcn_sched_barrier(0);
            if (tid == 0)
                __hip_atomic_store(prod + (size_t)nb * CNT_STRIDE, tgt + 1,
                                   __ATOMIC_RELAXED, __HIP_MEMORY_SCOPE_AGENT);
        }

        // ---- deferred cached out stores (off the publish critical path) ----
        {
            size_t ooff = ((size_t)t * BATCH + b_act) * HDIM + nb * UPB + u0;
            if (out_b) *(ushort2*)(out_b + ooff) = (ushort2){hb0, hb1};
            if (out_f) *(float2*)(out_f + ooff) = (float2){hv0, hv1};
        }

        // prefetch xproj for t+1
        {
            const unsigned short* xpb = xproj + ((size_t)(t + 1) * BATCH + b_act) * G4H + nb * UPB + u0;
#pragma unroll
            for (int g = 0; g < 4; g++) xpv[g] = *(const ushort2*)(xpb + g * HDIM);
        }
    }
}

extern "C" void kernel_launch(void* const* d_in, const int* in_sizes, int n_in,
                              void* d_out, int out_size, void* d_ws, size_t ws_size,
                              hipStream_t stream) {
    (void)in_sizes; (void)n_in; (void)out_size; (void)ws_size;
    const float* x    = (const float*)d_in[0];
    const float* Wih0 = (const float*)d_in[1];
    const float* Whh0 = (const float*)d_in[2];
    const float* bih0 = (const float*)d_in[3];
    const float* bhh0 = (const float*)d_in[4];
    const float* Wih1 = (const float*)d_in[5];
    const float* Whh1 = (const float*)d_in[6];
    const float* bih1 = (const float*)d_in[7];
    const float* bhh1 = (const float*)d_in[8];
    float* out = (float*)d_out;

    // ---- workspace layout ----
    unsigned short* xb0   = (unsigned short*)d_ws;                 // x bf16        [TB][1024]
    unsigned short* xb1   = xb0 + (size_t)TBROWS * HDIM;           // layer0 h bf16 [TB][1024]
    unsigned short* wb0   = xb1 + (size_t)TBROWS * HDIM;           // W_ih0 bf16
    unsigned short* wb1   = wb0 + (size_t)G4H * HDIM;              // W_ih1 bf16
    unsigned short* xproj = wb1 + (size_t)G4H * HDIM;              // x_proj bf16 [TB][4096]
    unsigned short* hhi   = xproj + (size_t)TBROWS * G4H;          // h hi [2][NBLK][64][8]
    unsigned short* hlo   = hhi + 2 * HB;                          // h lo [2][NBLK][64][8]
    float* bsum0          = (float*)(hlo + 2 * HB);                // b_ih+b_hh
    float* bsum1          = bsum0 + G4H;
    unsigned* bar         = (unsigned*)(bsum1 + G4H);              // flags + done lines

    float* hn0 = out + (size_t)TBROWS * HDIM;
    float* hn1 = hn0 + BATCH * HDIM;
    float* cn0 = hn1 + BATCH * HDIM;
    float* cn1 = cn0 + BATCH * HDIM;

    const unsigned lstm_lds = 32 * HDIM * 2 * 2 + 64 * 33 * 4 + 2 * 64 * 8 * 2;  // 141568 B
    static bool attr_set = false;
    if (!attr_set) {
        hipFuncSetAttribute((const void*)k_lstm,
                            hipFuncAttributeMaxDynamicSharedMemorySize, lstm_lds);
        attr_set = true;
    }

    // zero flag + done lines (ws is re-poisoned before every call)
    hipMemsetAsync(bar, 0, (NBLK + 2 * T_SEQ) * CNT_STRIDE * sizeof(unsigned), stream);

    // conversions
    k_cvt<<<(TBROWS * HDIM / 4 + 255) / 256, 256, 0, stream>>>(x, xb0, TBROWS * HDIM);
    k_cvt<<<(G4H * HDIM / 4 + 255) / 256, 256, 0, stream>>>(Wih0, wb0, G4H * HDIM);
    k_cvt<<<(G4H * HDIM / 4 + 255) / 256, 256, 0, stream>>>(Wih1, wb1, G4H * HDIM);
    k_bias<<<(2 * G4H + 255) / 256, 256, 0, stream>>>(bih0, bhh0, bih1, bhh1, bsum0, bsum1);

    dim3 gg(G4H / 128, TBROWS / 128);   // 32 x 256 blocks

    // layer 0
    k_gemm_bt<<<gg, 256, 0, stream>>>(xb0, wb0, bsum0, xproj, TBROWS, G4H, HDIM);
    {
        const float* whh = Whh0;
        const unsigned short* xp = xproj;
        unsigned short* hh = hhi; unsigned short* hl = hlo;
        unsigned short* ob = xb1;
        float* of = nullptr;
        float* hn = hn0; float* cn = cn0;
        unsigned* bp = bar; int bb = 0;
        void* args[] = {(void*)&whh, (void*)&xp, (void*)&hh, (void*)&hl,
                        (void*)&ob, (void*)&of, (void*)&hn, (void*)&cn,
                        (void*)&bp, (void*)&bb};
        hipLaunchCooperativeKernel((void*)k_lstm, dim3(NBLK), dim3(256), args, lstm_lds, stream);
    }

    // layer 1
    k_gemm_bt<<<gg, 256, 0, stream>>>(xb1, wb1, bsum1, xproj, TBROWS, G4H, HDIM);
    {
        const float* whh = Whh1;
        const unsigned short* xp = xproj;
        unsigned short* hh = hhi; unsigned short* hl = hlo;
        unsigned short* ob = nullptr;
        float* of = out;
        float* hn = hn1; float* cn = cn1;
        unsigned* bp = bar; int bb = T_SEQ;
        void* args[] = {(void*)&whh, (void*)&xp, (void*)&hh, (void*)&hl,
                        (void*)&ob, (void*)&of, (void*)&hn, (void*)&cn,
                        (void*)&bp, (void*)&bb};
        hipLaunchCooperativeKernel((void*)k_lstm, dim3(NBLK), dim3(256), args, lstm_lds, stream);
    }
}

// Round 6
// 8581.084 us; speedup vs baseline: 2.6937x; 1.0212x over previous
//
#include <hip/hip_runtime.h>

#define T_SEQ 512
#define BATCH 64
#define HDIM 1024
#define G4H 4096
#define TBROWS (T_SEQ * BATCH)   // 32768
#define NBLK 128                 // recurrence blocks
#define UPB 8                    // hidden units per block
#define CNT_STRIDE 16            // u32s between done lines (64B)
#define HB (NBLK * BATCH * UPB)  // shorts per h buffer (= B*H = 65536)

using short8  = __attribute__((ext_vector_type(8))) short;   // 8 bf16 (4 VGPRs)
using float4v = __attribute__((ext_vector_type(4))) float;   // MFMA C/D

__device__ __forceinline__ unsigned short f2bf(float f) {
    union { float f; unsigned int u; } v; v.f = f;
    return (unsigned short)((v.u + 0x7fffu + ((v.u >> 16) & 1u)) >> 16); // RNE
}
__device__ __forceinline__ float bf2f(unsigned short b) {
    union { unsigned int u; float f; } v; v.u = ((unsigned int)b) << 16;
    return v.f;
}

// ---------------- fp32 -> bf16 bulk convert ----------------
__global__ void k_cvt(const float* __restrict__ src, unsigned short* __restrict__ dst, int n) {
    int i = (blockIdx.x * 256 + threadIdx.x) * 4;
    if (i >= n) return;                 // n % 4 == 0 for all our uses
    float4 v = *(const float4*)(src + i);
    ushort4 o;
    o.x = f2bf(v.x); o.y = f2bf(v.y); o.z = f2bf(v.z); o.w = f2bf(v.w);
    *(ushort4*)(dst + i) = o;
}

__global__ void k_bias(const float* __restrict__ a0, const float* __restrict__ b0,
                       const float* __restrict__ a1, const float* __restrict__ b1,
                       float* __restrict__ s0, float* __restrict__ s1) {
    int t = blockIdx.x * 256 + threadIdx.x;
    if (t < G4H) s0[t] = a0[t] + b0[t];
    else if (t < 2 * G4H) s1[t - G4H] = a1[t - G4H] + b1[t - G4H];
}

// ---------------- bf16 MFMA GEMM: C[M,N] = A[M,K] * B[N,K]^T + bias ----------------
__global__ __launch_bounds__(256) void k_gemm_bt(
    const unsigned short* __restrict__ A,
    const unsigned short* __restrict__ B,
    const float* __restrict__ bias,
    unsigned short* __restrict__ C,
    int M, int N, int K)
{
    __shared__ __align__(16) unsigned short Asm[128 * 64];
    __shared__ __align__(16) unsigned short Bsm[128 * 64];

    const int w    = threadIdx.x >> 6;
    const int lane = threadIdx.x & 63;
    const int q    = lane >> 4, r15 = lane & 15;
    const int m0   = blockIdx.y * 128;
    const int n0   = blockIdx.x * 128;
    const int wm   = w & 1, wn = w >> 1;

    float4v acc[4][4];
#pragma unroll
    for (int i = 0; i < 4; i++)
#pragma unroll
        for (int j = 0; j < 4; j++) acc[i][j] = (float4v){0.f, 0.f, 0.f, 0.f};

    for (int k0 = 0; k0 < K; k0 += 64) {
        __syncthreads();
#pragma unroll
        for (int ii = 0; ii < 4; ii++) {
            int plin = (ii * 4 + w) * 64 + lane;
            int row  = plin >> 3;
            int gch  = (plin & 7) ^ (row & 7);
            const unsigned short* ga = A + (size_t)(m0 + row) * K + (k0 + gch * 8);
            const unsigned short* gb = B + (size_t)(n0 + row) * K + (k0 + gch * 8);
            __builtin_amdgcn_global_load_lds((const __attribute__((address_space(1))) void*)ga,
                                             (__attribute__((address_space(3))) void*)(Asm + plin * 8),
                                             16, 0, 0);
            __builtin_amdgcn_global_load_lds((const __attribute__((address_space(1))) void*)gb,
                                             (__attribute__((address_space(3))) void*)(Bsm + plin * 8),
                                             16, 0, 0);
        }
        __syncthreads();
#pragma unroll
        for (int kh = 0; kh < 2; kh++) {
            short8 af[4], bfr[4];
#pragma unroll
            for (int mi = 0; mi < 4; mi++) {
                int row = wm * 64 + mi * 16 + r15;
                int ch  = (kh * 4 + q) ^ (row & 7);
                af[mi]  = *(const short8*)(Asm + (row * 8 + ch) * 8);
            }
#pragma unroll
            for (int ni = 0; ni < 4; ni++) {
                int row = wn * 64 + ni * 16 + r15;
                int ch  = (kh * 4 + q) ^ (row & 7);
                bfr[ni] = *(const short8*)(Bsm + (row * 8 + ch) * 8);
            }
#pragma unroll
            for (int mi = 0; mi < 4; mi++)
#pragma unroll
                for (int ni = 0; ni < 4; ni++)
                    acc[mi][ni] = __builtin_amdgcn_mfma_f32_16x16x32_bf16(af[mi], bfr[ni], acc[mi][ni], 0, 0, 0);
        }
    }

#pragma unroll
    for (int ni = 0; ni < 4; ni++) {
        int col  = n0 + wn * 64 + ni * 16 + r15;
        float bv = bias[col];
#pragma unroll
        for (int mi = 0; mi < 4; mi++) {
            int rowb = m0 + wm * 64 + mi * 16 + q * 4;
#pragma unroll
            for (int rr = 0; rr < 4; rr++)
                C[(size_t)(rowb + rr) * N + col] = f2bf(acc[mi][ni][rr] + bv);
        }
    }
}

// uncached (device-coherent, L1+L2 bypass) accesses
#define LD16U(dst, ptr) \
    asm volatile("global_load_dwordx4 %0, %1, off sc0 sc1" : "=v"(dst) : "v"(ptr))
#define ST4U(ptr, val) \
    asm volatile("global_store_dword %0, %1, off sc0 sc1" :: "v"(ptr), "v"(val) : "memory")

#define VMWAIT(N) do { \
    asm volatile("s_waitcnt vmcnt(" #N ")" ::: "memory"); \
    __builtin_amdgcn_sched_barrier(0); \
} while (0)

// gate: wait until the 32 producer blocks of k-group g have published step tgt.
// flags are PACKED (4B stride): lanes 0-31 read one 128B line -> 1 MALL txn/poll.
__device__ __forceinline__ void gate(const unsigned* prod, int g, unsigned tgt, int lane) {
    if (lane < 32) {
        const unsigned* f = prod + g * 32 + lane;
        while (__hip_atomic_load(f, __ATOMIC_RELAXED, __HIP_MEMORY_SCOPE_AGENT) < tgt)
            __builtin_amdgcn_s_sleep(1);
    }
    __builtin_amdgcn_sched_barrier(0);
}

// issue 8 kc x (hi,lo) uncached loads for group g (chunked h layout)
__device__ __forceinline__ void issue_grp(const unsigned short* hb, const unsigned short* lb,
                                          short8 (&H)[8], short8 (&L)[8]) {
#pragma unroll
    for (int i = 0; i < 8; i++) {
        LD16U(H[i], hb + i * 2048);
        LD16U(L[i], lb + i * 2048);
    }
}

// MFMA one group of 8 kc (runtime g) against W in LDS
__device__ __forceinline__ void mfma_grp(int g, const short8 (&ah)[8], const short8 (&al)[8],
                                         const unsigned short* Whi, const unsigned short* Wlo,
                                         int q, int r15, float4v (&acc)[2][3])
{
#pragma unroll
    for (int i = 0; i < 8; i++) {
        const int kc = g * 8 + i;
#pragma unroll
        for (int jg = 0; jg < 2; jg++) {
            const unsigned short* bb = Whi + jg * 16 * HDIM + (kc * 4 + q) * 128 + r15 * 8;
            const unsigned short* bl = Wlo + jg * 16 * HDIM + (kc * 4 + q) * 128 + r15 * 8;
            short8 bh  = *(const short8*)bb;
            short8 blv = *(const short8*)bl;
            acc[jg][0] = __builtin_amdgcn_mfma_f32_16x16x32_bf16(ah[i], bh,  acc[jg][0], 0, 0, 0);
            acc[jg][1] = __builtin_amdgcn_mfma_f32_16x16x32_bf16(al[i], bh,  acc[jg][1], 0, 0, 0);
            acc[jg][2] = __builtin_amdgcn_mfma_f32_16x16x32_bf16(ah[i], blv, acc[jg][2], 0, 0, 0);
        }
    }
}

// ---------------- persistent LSTM recurrence ----------------
// R6 == R5 design + explicit vmcnt(0) drain before the flag publish.
// (Inline-asm stores are NOT tracked by the compiler's pre-barrier waitcnt
// insertion, so __syncthreads() alone does not guarantee the uncached h
// stores are durable before the flag store becomes visible.)
// - flags packed 4B apart -> gate poll = 1 coalesced 128B MALL txn (was 32).
// - producer publish: every thread stores its own (hi,lo) u32 directly
//   (4B/lane fully coalesced); explicit vmcnt(0); syncthreads; tid0 flag.
// - h uncached (sc0 sc1) both directions; no fences/invalidates anywhere.
__global__ __launch_bounds__(256) void k_lstm(
    const float* __restrict__ Whh,            // [4096][1024] fp32
    const unsigned short* __restrict__ xproj, // [T*B][4096] bf16 (bias included)
    unsigned short* __restrict__ h_hi,        // [2][NBLK][64][8] bf16 chunked
    unsigned short* __restrict__ h_lo,        // [2][NBLK][64][8] bf16 chunked
    unsigned short* __restrict__ out_b,       // layer0: bf16 h for layer-1 GEMM (or null)
    float* __restrict__ out_f,                // layer1: fp32 h -> d_out (or null)
    float* __restrict__ hn, float* __restrict__ cn,
    unsigned* __restrict__ bar,               // [NBLK] packed flags + [2*T_SEQ] done lines
    int bar_base)                             // 0 for layer0, T_SEQ for layer1
{
    extern __shared__ char smem[];
    unsigned short* Whi = (unsigned short*)smem;        // [2 jg][128 kgran][16 j][8]  64 KB
    unsigned short* Wlo = Whi + 32 * HDIM;              // 64 KB
    float* glds         = (float*)(Wlo + 32 * HDIM);    // [64][33] gates (pad)

    const int nb   = blockIdx.x;
    const int tid  = threadIdx.x;
    const int w    = tid >> 6;
    const int lane = tid & 63;
    const int q    = lane >> 4, r15 = lane & 15;
    const int brow = w * 16 + r15;

    unsigned* prod = bar;                          // NBLK packed flags (4B stride)
    unsigned* done = bar + NBLK;                   // per-abs-step counter lines (64B stride)

    // ---- stage W_hh slice: fp32 -> bf16 hi/lo, B-fragment order ----
    {
        int j    = tid >> 3;              // 0..31, j = gate*8 + unit
        int g    = j >> 3, ui = j & 7;
        int jg   = j >> 4, jloc = j & 15;
        size_t grow = (size_t)(g * HDIM + nb * UPB + ui) * HDIM;
        unsigned short* whiB = Whi + jg * 16 * HDIM;
        unsigned short* wloB = Wlo + jg * 16 * HDIM;
        int kbase = (tid & 7) * 128;
        for (int e = 0; e < 128; e += 4) {
            int k = kbase + e;
            float4 wv = *(const float4*)(Whh + grow + k);
            float vv[4] = {wv.x, wv.y, wv.z, wv.w};
            unsigned short hs[4], ls[4];
#pragma unroll
            for (int m = 0; m < 4; m++) {
                hs[m] = f2bf(vv[m]);
                ls[m] = f2bf(vv[m] - bf2f(hs[m]));
            }
            int addr = (k >> 3) * 128 + jloc * 8 + (k & 7);   // shorts
            *(ushort4*)(whiB + addr) = (ushort4){hs[0], hs[1], hs[2], hs[3]};
            *(ushort4*)(wloB + addr) = (ushort4){ls[0], ls[1], ls[2], ls[3]};
        }
    }

    const int b_act = tid >> 2;                 // batch row for activation
    const int u0    = (tid & 3) * 2;            // local units u0, u0+1
    float c0 = 0.f, c1 = 0.f;

    // prefetch xproj for t=0 (h-independent)
    ushort2 xpv[4];
    {
        const unsigned short* xpb = xproj + (size_t)b_act * G4H + nb * UPB + u0;
#pragma unroll
        for (int g = 0; g < 4; g++) xpv[g] = *(const ushort2*)(xpb + g * HDIM);
    }

    __syncthreads();

    for (int t = 0; t < T_SEQ; t++) {
        const int cur = t & 1, nxt = cur ^ 1;
        const unsigned tgt = (unsigned)(bar_base + t);   // flag value that publishes h_t

        // prefetch WAR check value (1-step-slack done counter), resolved at store time
        unsigned done_pre = NBLK;
        if (t >= 2)
            done_pre = __hip_atomic_load(done + (size_t)(bar_base + t - 1) * CNT_STRIDE,
                                         __ATOMIC_RELAXED, __HIP_MEMORY_SCOPE_AGENT);

        // ---- recurrent GEMM: gates[b][j] += h_t . W_hh[j] (hi/lo 3-product) ----
        float4v acc[2][3];
#pragma unroll
        for (int jg = 0; jg < 2; jg++)
#pragma unroll
            for (int p = 0; p < 3; p++) acc[jg][p] = (float4v){0.f, 0.f, 0.f, 0.f};

        if (t > 0) {
            const unsigned short* hbase = h_hi + (size_t)cur * HB + q * 512 + brow * 8;
            const unsigned short* lbase = h_lo + (size_t)cur * HB + q * 512 + brow * 8;
            short8 H0[8], L0[8], H1[8], L1[8];
            const int g0 = nb & 3;
            const int gA = g0, gB = (g0 + 1) & 3, gC = (g0 + 2) & 3, gD = (g0 + 3) & 3;

            gate(prod, gA, tgt, lane);
            issue_grp(hbase + gA * 16384, lbase + gA * 16384, H0, L0);
            gate(prod, gB, tgt, lane);
            issue_grp(hbase + gB * 16384, lbase + gB * 16384, H1, L1);
            VMWAIT(16);
            mfma_grp(gA, H0, L0, Whi, Wlo, q, r15, acc);
            gate(prod, gC, tgt, lane);
            issue_grp(hbase + gC * 16384, lbase + gC * 16384, H0, L0);
            VMWAIT(16);
            mfma_grp(gB, H1, L1, Whi, Wlo, q, r15, acc);
            gate(prod, gD, tgt, lane);
            issue_grp(hbase + gD * 16384, lbase + gD * 16384, H1, L1);
            VMWAIT(16);
            mfma_grp(gC, H0, L0, Whi, Wlo, q, r15, acc);
            VMWAIT(0);
            mfma_grp(gD, H1, L1, Whi, Wlo, q, r15, acc);
        }

        // gates -> LDS: D row=(q*4+rr) -> batch, col=r15 -> j within group
#pragma unroll
        for (int jg = 0; jg < 2; jg++) {
            int browg = w * 16 + q * 4;
#pragma unroll
            for (int rr = 0; rr < 4; rr++)
                glds[(browg + rr) * 33 + jg * 16 + r15] = acc[jg][0][rr] + acc[jg][1][rr] + acc[jg][2][rr];
        }
        __syncthreads();   // gates visible; also: all waves' h loads of step t retired

        if (t > 0 && tid == 0)
            __hip_atomic_fetch_add(done + (size_t)(bar_base + t) * CNT_STRIDE, 1u,
                                   __ATOMIC_RELAXED, __HIP_MEMORY_SCOPE_AGENT);

        // ---- activations: thread -> (batch b_act, units u0,u0+1) ----
        float hv0, hv1;
        {
            const float* gr = glds + b_act * 33;
            float gi0 = gr[0*8 + u0]     + bf2f(xpv[0].x);
            float gi1 = gr[0*8 + u0 + 1] + bf2f(xpv[0].y);
            float gf0 = gr[1*8 + u0]     + bf2f(xpv[1].x);
            float gf1 = gr[1*8 + u0 + 1] + bf2f(xpv[1].y);
            float gg0 = gr[2*8 + u0]     + bf2f(xpv[2].x);
            float gg1 = gr[2*8 + u0 + 1] + bf2f(xpv[2].y);
            float go0 = gr[3*8 + u0]     + bf2f(xpv[3].x);
            float go1 = gr[3*8 + u0 + 1] + bf2f(xpv[3].y);

            c0 = (1.f / (1.f + __expf(-gf0))) * c0 + (1.f / (1.f + __expf(-gi0))) * tanhf(gg0);
            c1 = (1.f / (1.f + __expf(-gf1))) * c1 + (1.f / (1.f + __expf(-gi1))) * tanhf(gg1);
            hv0 = (1.f / (1.f + __expf(-go0))) * tanhf(c0);
            hv1 = (1.f / (1.f + __expf(-go1))) * tanhf(c1);
        }
        unsigned short hb0 = f2bf(hv0), hb1 = f2bf(hv1);

        if (t == T_SEQ - 1) {
            size_t ooff = ((size_t)t * BATCH + b_act) * HDIM + nb * UPB + u0;
            if (out_b) *(ushort2*)(out_b + ooff) = (ushort2){hb0, hb1};
            if (out_f) *(float2*)(out_f + ooff) = (float2){hv0, hv1};
            int hidx = b_act * HDIM + nb * UPB + u0;
            hn[hidx] = hv0; hn[hidx + 1] = hv1;
            cn[hidx] = c0;  cn[hidx + 1] = c1;
            break;
        }

        // ---- WAR gate (per-thread, usually satisfied by prefetched value) ----
        if (t >= 2) {
            while (done_pre < (unsigned)NBLK) {
                __builtin_amdgcn_s_sleep(1);
                done_pre = __hip_atomic_load(done + (size_t)(bar_base + t - 1) * CNT_STRIDE,
                                             __ATOMIC_RELAXED, __HIP_MEMORY_SCOPE_AGENT);
            }
        }
        __builtin_amdgcn_sched_barrier(0);

        // ---- direct uncached h publish: 4B/lane, fully coalesced ----
        {
            unsigned short lb0 = f2bf(hv0 - bf2f(hb0)), lb1 = f2bf(hv1 - bf2f(hb1));
            unsigned hpack = (unsigned)hb0 | ((unsigned)hb1 << 16);
            unsigned lpack = (unsigned)lb0 | ((unsigned)lb1 << 16);
            unsigned short* dh = h_hi + (size_t)nxt * HB + nb * 512 + tid * 2;
            unsigned short* dl = h_lo + (size_t)nxt * HB + nb * 512 + tid * 2;
            ST4U(dh, hpack);
            ST4U(dl, lpack);
        }
        // explicit drain: inline-asm stores are invisible to the compiler's
        // pre-barrier waitcnt insertion -> must wait vmcnt(0) ourselves.
        asm volatile("s_waitcnt vmcnt(0)" ::: "memory");
        __builtin_amdgcn_sched_barrier(0);
        __syncthreads();   // all waves' h stores durable at MALL
        if (tid == 0)
            __hip_atomic_store(prod + nb, tgt + 1, __ATOMIC_RELAXED, __HIP_MEMORY_SCOPE_AGENT);

        // ---- deferred cached out stores (off the publish critical path) ----
        {
            size_t ooff = ((size_t)t * BATCH + b_act) * HDIM + nb * UPB + u0;
            if (out_b) *(ushort2*)(out_b + ooff) = (ushort2){hb0, hb1};
            if (out_f) *(float2*)(out_f + ooff) = (float2){hv0, hv1};
        }

        // prefetch xproj for t+1
        {
            const unsigned short* xpb = xproj + ((size_t)(t + 1) * BATCH + b_act) * G4H + nb * UPB + u0;
#pragma unroll
            for (int g = 0; g < 4; g++) xpv[g] = *(const ushort2*)(xpb + g * HDIM);
        }
    }
}

extern "C" void kernel_launch(void* const* d_in, const int* in_sizes, int n_in,
                              void* d_out, int out_size, void* d_ws, size_t ws_size,
                              hipStream_t stream) {
    (void)in_sizes; (void)n_in; (void)out_size; (void)ws_size;
    const float* x    = (const float*)d_in[0];
    const float* Wih0 = (const float*)d_in[1];
    const float* Whh0 = (const float*)d_in[2];
    const float* bih0 = (const float*)d_in[3];
    const float* bhh0 = (const float*)d_in[4];
    const float* Wih1 = (const float*)d_in[5];
    const float* Whh1 = (const float*)d_in[6];
    const float* bih1 = (const float*)d_in[7];
    const float* bhh1 = (const float*)d_in[8];
    float* out = (float*)d_out;

    // ---- workspace layout ----
    unsigned short* xb0   = (unsigned short*)d_ws;                 // x bf16        [TB][1024]
    unsigned short* xb1   = xb0 + (size_t)TBROWS * HDIM;           // layer0 h bf16 [TB][1024]
    unsigned short* wb0   = xb1 + (size_t)TBROWS * HDIM;           // W_ih0 bf16
    unsigned short* wb1   = wb0 + (size_t)G4H * HDIM;              // W_ih1 bf16
    unsigned short* xproj = wb1 + (size_t)G4H * HDIM;              // x_proj bf16 [TB][4096]
    unsigned short* hhi   = xproj + (size_t)TBROWS * G4H;          // h hi [2][NBLK][64][8]
    unsigned short* hlo   = hhi + 2 * HB;                          // h lo [2][NBLK][64][8]
    float* bsum0          = (float*)(hlo + 2 * HB);                // b_ih+b_hh
    float* bsum1          = bsum0 + G4H;
    unsigned* bar         = (unsigned*)(bsum1 + G4H);              // packed flags + done lines

    float* hn0 = out + (size_t)TBROWS * HDIM;
    float* hn1 = hn0 + BATCH * HDIM;
    float* cn0 = hn1 + BATCH * HDIM;
    float* cn1 = cn0 + BATCH * HDIM;

    const unsigned lstm_lds = 32 * HDIM * 2 * 2 + 64 * 33 * 4;  // 139520 B
    static bool attr_set = false;
    if (!attr_set) {
        hipFuncSetAttribute((const void*)k_lstm,
                            hipFuncAttributeMaxDynamicSharedMemorySize, lstm_lds);
        attr_set = true;
    }

    // zero flags (NBLK u32 packed) + done lines (ws is re-poisoned before every call)
    hipMemsetAsync(bar, 0, (NBLK + 2 * T_SEQ * CNT_STRIDE) * sizeof(unsigned), stream);

    // conversions
    k_cvt<<<(TBROWS * HDIM / 4 + 255) / 256, 256, 0, stream>>>(x, xb0, TBROWS * HDIM);
    k_cvt<<<(G4H * HDIM / 4 + 255) / 256, 256, 0, stream>>>(Wih0, wb0, G4H * HDIM);
    k_cvt<<<(G4H * HDIM / 4 + 255) / 256, 256, 0, stream>>>(Wih1, wb1, G4H * HDIM);
    k_bias<<<(2 * G4H + 255) / 256, 256, 0, stream>>>(bih0, bhh0, bih1, bhh1, bsum0, bsum1);

    dim3 gg(G4H / 128, TBROWS / 128);   // 32 x 256 blocks

    // layer 0
    k_gemm_bt<<<gg, 256, 0, stream>>>(xb0, wb0, bsum0, xproj, TBROWS, G4H, HDIM);
    {
        const float* whh = Whh0;
        const unsigned short* xp = xproj;
        unsigned short* hh = hhi; unsigned short* hl = hlo;
        unsigned short* ob = xb1;
        float* of = nullptr;
        float* hn = hn0; float* cn = cn0;
        unsigned* bp = bar; int bb = 0;
        void* args[] = {(void*)&whh, (void*)&xp, (void*)&hh, (void*)&hl,
                        (void*)&ob, (void*)&of, (void*)&hn, (void*)&cn,
                        (void*)&bp, (void*)&bb};
        hipLaunchCooperativeKernel((void*)k_lstm, dim3(NBLK), dim3(256), args, lstm_lds, stream);
    }

    // layer 1
    k_gemm_bt<<<gg, 256, 0, stream>>>(xb1, wb1, bsum1, xproj, TBROWS, G4H, HDIM);
    {
        const float* whh = Whh1;
        const unsigned short* xp = xproj;
        unsigned short* hh = hhi; unsigned short* hl = hlo;
        unsigned short* ob = nullptr;
        float* of = out;
        float* hn = hn1; float* cn = cn1;
        unsigned* bp = bar; int bb = T_SEQ;
        void* args[] = {(void*)&whh, (void*)&xp, (void*)&hh, (void*)&hl,
                        (void*)&ob, (void*)&of, (void*)&hn, (void*)&cn,
                        (void*)&bp, (void*)&bb};
        hipLaunchCooperativeKernel((void*)k_lstm, dim3(NBLK), dim3(256), args, lstm_lds, stream);
    }
}